// Round 1
// baseline (2587.975 us; speedup 1.0000x reference)
//
#include <hip/hip_runtime.h>

#define S 1024
#define D 512
#define HID 64
#define CD 32768
#define DT 0.1f

// ---------------- GEMM: C[m,n] = sum_k A[m*K+k] * B[n*K+k]  (C = A @ B^T) ----
__global__ __launch_bounds__(256) void gemm_abT(const float* __restrict__ A,
                                                const float* __restrict__ B,
                                                float* __restrict__ C,
                                                int M, int N, int K) {
  __shared__ float As[64][17];
  __shared__ float Bs[64][17];
  const int tx = threadIdx.x & 15;   // n-tile
  const int ty = threadIdx.x >> 4;   // m-tile
  const int m0 = blockIdx.y * 64, n0 = blockIdx.x * 64;
  float acc[4][4] = {};
  for (int k0 = 0; k0 < K; k0 += 16) {
#pragma unroll
    for (int r = 0; r < 4; ++r) {
      int row = ty + r * 16;
      As[row][tx] = A[(m0 + row) * K + k0 + tx];
      Bs[row][tx] = B[(n0 + row) * K + k0 + tx];
    }
    __syncthreads();
#pragma unroll
    for (int kk = 0; kk < 16; ++kk) {
      float a[4], b[4];
#pragma unroll
      for (int i = 0; i < 4; ++i) a[i] = As[ty * 4 + i][kk];
#pragma unroll
      for (int j = 0; j < 4; ++j) b[j] = Bs[tx * 4 + j][kk];
#pragma unroll
      for (int i = 0; i < 4; ++i)
#pragma unroll
        for (int j = 0; j < 4; ++j) acc[i][j] += a[i] * b[j];
    }
    __syncthreads();
  }
#pragma unroll
  for (int i = 0; i < 4; ++i)
#pragma unroll
    for (int j = 0; j < 4; ++j)
      C[(m0 + ty * 4 + i) * N + n0 + tx * 4 + j] = acc[i][j];
}

// ---------------- Shift SSM on K: 64-tap causal FIR + skip ------------------
__global__ void shift_ssm(const float* __restrict__ Kin, const float* __restrict__ Cs,
                          const float* __restrict__ Ds, float* __restrict__ Kout) {
  const int t = blockIdx.x;
  const int d = threadIdx.x;          // 512 threads
  float acc = Ds[d] * Kin[t * D + d];
  const int jmax = t < 63 ? t : 63;
  for (int j = 0; j <= jmax; ++j)
    acc += Cs[d * HID + j] * Kin[(t - j) * D + d];
  Kout[t * D + d] = acc;
}

// ---------------- S4D diagonal SSM: wave-per-channel recurrent scan ---------
// Channel c = h*4096 + i*64 + j;  u[c,t] = Kn[t, h*64+i] * V[t, h*64+j].
// Lane n holds complex state x_n: x = dA_n * x + u;  y = 2*Re(sum_n CB_n x_n) + Dd*u.
__global__ __launch_bounds__(256) void s4d_scan(
    const float* __restrict__ Kn, const float* __restrict__ V,
    const float* __restrict__ Are, const float* __restrict__ Aim,
    const float* __restrict__ Cre, const float* __restrict__ Cim,
    const float* __restrict__ Dd, float* __restrict__ Y) {
  const int lane = threadIdx.x & 63;                 // state index n
  const int c = blockIdx.x * 4 + (threadIdx.x >> 6); // channel
  const int dk = c >> 6;                             // h*64 + i
  const int dv = ((c >> 12) << 6) | (c & 63);        // h*64 + j

  // bilinear discretization: dA = (1 + DT*A/2)/(1 - DT*A/2), dB = DT/(1 - DT*A/2)
  const float ar = Are[lane], ai = Aim[lane];
  const float den_re = 1.0f - 0.05f * ar;
  const float den_im = -0.05f * ai;
  const float num_re = 1.0f + 0.05f * ar;
  const float num_im = 0.05f * ai;
  const float inv_d2 = 1.0f / (den_re * den_re + den_im * den_im);
  const float dA_re = (num_re * den_re + num_im * den_im) * inv_d2;
  const float dA_im = (num_im * den_re - num_re * den_im) * inv_d2;
  const float dB_re = DT * den_re * inv_d2;
  const float dB_im = -DT * den_im * inv_d2;

  const float cr = Cre[c * HID + lane], ci = Cim[c * HID + lane];
  const float CBre = cr * dB_re - ci * dB_im;
  const float CBim = cr * dB_im + ci * dB_re;
  const float dskip = Dd[c];

  float xr = 0.0f, xi = 0.0f;
  for (int t = 0; t < S; ++t) {
    const float u = Kn[t * D + dk] * V[t * D + dv];
    const float nxr = dA_re * xr - dA_im * xi + u;
    const float nxi = dA_re * xi + dA_im * xr;
    xr = nxr;
    xi = nxi;
    float p = CBre * xr - CBim * xi;
#pragma unroll
    for (int off = 32; off > 0; off >>= 1) p += __shfl_xor(p, off, 64);
    if (lane == 0) Y[t * CD + c] = 2.0f * p + dskip * u;
  }
}

// ---------------- O[t, h*64+j] = sum_i Q[t,h*64+i] * Y[t, h*4096+i*64+j] ----
__global__ void contract_q(const float* __restrict__ Q, const float* __restrict__ Y,
                           float* __restrict__ O1) {
  const int t = blockIdx.x;
  const int tid = threadIdx.x;        // 512 threads: h = tid>>6, j = tid&63
  const int h = tid >> 6, j = tid & 63;
  const float* Yt = Y + t * CD + (h << 12) + j;
  const float* Qt = Q + t * D + (h << 6);
  float acc = 0.0f;
#pragma unroll 8
  for (int i = 0; i < 64; ++i) acc += Qt[i] * Yt[i << 6];
  O1[t * D + tid] = acc;
}

extern "C" void kernel_launch(void* const* d_in, const int* in_sizes, int n_in,
                              void* d_out, int out_size, void* d_ws, size_t ws_size,
                              hipStream_t stream) {
  const float* x   = (const float*)d_in[0];
  const float* WQ  = (const float*)d_in[1];
  const float* WK  = (const float*)d_in[2];
  const float* WV  = (const float*)d_in[3];
  const float* WO  = (const float*)d_in[4];
  const float* Cs  = (const float*)d_in[5];
  const float* Ds  = (const float*)d_in[6];
  const float* Are = (const float*)d_in[7];
  const float* Aim = (const float*)d_in[8];
  const float* Cre = (const float*)d_in[9];
  const float* Cim = (const float*)d_in[10];
  const float* Dd  = (const float*)d_in[11];
  float* out = (float*)d_out;

  float* ws   = (float*)d_ws;
  float* Q    = ws;            // 1024*512
  float* Kraw = Q + S * D;     // 1024*512
  float* V    = Kraw + S * D;  // 1024*512
  float* Kn   = V + S * D;     // 1024*512
  float* O1   = Kn + S * D;    // 1024*512
  float* Y    = O1 + S * D;    // 1024*32768  (t-major)

  dim3 ggrid(D / 64, S / 64);  // (8, 16)
  gemm_abT<<<ggrid, 256, 0, stream>>>(x, WQ, Q, S, D, D);
  gemm_abT<<<ggrid, 256, 0, stream>>>(x, WK, Kraw, S, D, D);
  gemm_abT<<<ggrid, 256, 0, stream>>>(x, WV, V, S, D, D);
  shift_ssm<<<S, D, 0, stream>>>(Kraw, Cs, Ds, Kn);
  s4d_scan<<<CD / 4, 256, 0, stream>>>(Kn, V, Are, Aim, Cre, Cim, Dd, Y);
  contract_q<<<S, D, 0, stream>>>(Q, Y, O1);
  gemm_abT<<<ggrid, 256, 0, stream>>>(O1, WO, out, S, D, D);
}

// Round 2
// 886.909 us; speedup vs baseline: 2.9180x; 2.9180x over previous
//
#include <hip/hip_runtime.h>

#define S 1024
#define D 512
#define HID 64
#define CD 32768
#define DT 0.1f

// ---------------- GEMM: C[m,n] = sum_k A[m*K+k] * B[n*K+k]  (C = A @ B^T) ----
__global__ __launch_bounds__(256) void gemm_abT(const float* __restrict__ A,
                                                const float* __restrict__ B,
                                                float* __restrict__ C,
                                                int M, int N, int K) {
  __shared__ float As[64][17];
  __shared__ float Bs[64][17];
  const int tx = threadIdx.x & 15;
  const int ty = threadIdx.x >> 4;
  const int m0 = blockIdx.y * 64, n0 = blockIdx.x * 64;
  float acc[4][4] = {};
  for (int k0 = 0; k0 < K; k0 += 16) {
#pragma unroll
    for (int r = 0; r < 4; ++r) {
      int row = ty + r * 16;
      As[row][tx] = A[(m0 + row) * K + k0 + tx];
      Bs[row][tx] = B[(n0 + row) * K + k0 + tx];
    }
    __syncthreads();
#pragma unroll
    for (int kk = 0; kk < 16; ++kk) {
      float a[4], b[4];
#pragma unroll
      for (int i = 0; i < 4; ++i) a[i] = As[ty * 4 + i][kk];
#pragma unroll
      for (int j = 0; j < 4; ++j) b[j] = Bs[tx * 4 + j][kk];
#pragma unroll
      for (int i = 0; i < 4; ++i)
#pragma unroll
        for (int j = 0; j < 4; ++j) acc[i][j] += a[i] * b[j];
    }
    __syncthreads();
  }
#pragma unroll
  for (int i = 0; i < 4; ++i)
#pragma unroll
    for (int j = 0; j < 4; ++j)
      C[(m0 + ty * 4 + i) * N + n0 + tx * 4 + j] = acc[i][j];
}

// ---------------- Shift SSM on K: 64-tap causal FIR + skip ------------------
__global__ void shift_ssm(const float* __restrict__ Kin, const float* __restrict__ Cs,
                          const float* __restrict__ Ds, float* __restrict__ Kout) {
  const int t = blockIdx.x;
  const int d = threadIdx.x;
  float acc = Ds[d] * Kin[t * D + d];
  const int jmax = t < 63 ? t : 63;
  for (int j = 0; j <= jmax; ++j)
    acc += Cs[d * HID + j] * Kin[(t - j) * D + d];
  Kout[t * D + d] = acc;
}

// ---------------- 2 MB fp32 transpose: in[R][Cc] -> out[Cc][R] --------------
__global__ __launch_bounds__(256) void transpose_fp32(const float* __restrict__ in,
                                                      float* __restrict__ out,
                                                      int R, int Cc) {
  __shared__ float tile[32][33];
  const int bx = blockIdx.x * 32;  // col base
  const int by = blockIdx.y * 32;  // row base
  const int lx = threadIdx.x & 31, ly = threadIdx.x >> 5;
#pragma unroll
  for (int m = 0; m < 32; m += 8)
    tile[ly + m][lx] = in[(by + ly + m) * Cc + bx + lx];
  __syncthreads();
#pragma unroll
  for (int m = 0; m < 32; m += 8)
    out[(bx + ly + m) * R + by + lx] = tile[lx][ly + m];
}

// ---------------- S4D diagonal SSM: chunked, one block per channel ----------
// 16 chunks of length 64. Phase A: chunk-local state sums via Pow table.
// Phase B: 16-step chunk-state scan (wave 0) + kd taps build (wave 1).
// Phase C: y = inter-chunk (states x dA^{r+1}) + intra-chunk conv (kd_ext).
__global__ __launch_bounds__(256) void s4d_chunked(
    const float* __restrict__ KnT, const float* __restrict__ VT,
    const float* __restrict__ Are, const float* __restrict__ Aim,
    const float* __restrict__ Cre, const float* __restrict__ Cim,
    const float* __restrict__ Dd, float* __restrict__ Y) {
  __shared__ __align__(16) float PowRe[65][66];   // dA^k, k=0..64
  __shared__ __align__(16) float PowIm[65][66];
  __shared__ __align__(16) float uT[64][20];      // [r][g], pad->20
  __shared__ __align__(16) float XL[16][64][2];   // s' then 2CB*state-before-chunk
  __shared__ __align__(16) float CB2[64][2];      // 2*CB (complex)
  __shared__ __align__(16) float kd_ext[128];     // kd_ext[63+d]=kd[d]; [0..62]=0

  const int tid = threadIdx.x;
  const int c = blockIdx.x;
  const int dk = c >> 6;                           // h*64+i
  const int dv = ((c >> 12) << 6) | (c & 63);      // h*64+j

  // ---- setup: discretization, Pow table (dA^k), CB2, u ----
  {
    const int n = tid & 63, seg = tid >> 6;
    const float ar = Are[n], ai = Aim[n];
    const float den_re = 1.0f - 0.05f * ar;
    const float den_im = -0.05f * ai;
    const float num_re = 1.0f + 0.05f * ar;
    const float num_im = 0.05f * ai;
    const float inv_d2 = 1.0f / (den_re * den_re + den_im * den_im);
    const float dAr = (num_re * den_re + num_im * den_im) * inv_d2;
    const float dAi = (num_im * den_re - num_re * den_im) * inv_d2;
    // dA^16 via squarings
    float e2r = dAr * dAr - dAi * dAi, e2i = 2.0f * dAr * dAi;
    float e4r = e2r * e2r - e2i * e2i, e4i = 2.0f * e2r * e2i;
    float e8r = e4r * e4r - e4i * e4i, e8i = 2.0f * e4r * e4i;
    float e16r = e8r * e8r - e8i * e8i, e16i = 2.0f * e8r * e8i;
    // base = dA^(16*seg)
    float br = 1.0f, bi = 0.0f;
    for (int sgo = 0; sgo < seg; ++sgo) {
      float nr = br * e16r - bi * e16i;
      bi = br * e16i + bi * e16r;
      br = nr;
    }
    float pr = br, pi = bi;
    for (int k = 16 * seg + 1; k <= 16 * seg + 16; ++k) {
      float nr = pr * dAr - pi * dAi;
      pi = pr * dAi + pi * dAr;
      pr = nr;
      PowRe[k][n] = pr;
      PowIm[k][n] = pi;
    }
    if (seg == 0) {
      PowRe[0][n] = 1.0f;
      PowIm[0][n] = 0.0f;
      const float dBr = DT * den_re * inv_d2;
      const float dBi = -DT * den_im * inv_d2;
      const float cr = Cre[(c << 6) + n], ci = Cim[(c << 6) + n];
      CB2[n][0] = 2.0f * (cr * dBr - ci * dBi);
      CB2[n][1] = 2.0f * (cr * dBi + ci * dBr);
    }
    // u fill: coalesced float4 from transposed Kn, V
    const float4 kx = *(const float4*)&KnT[dk * S + 4 * tid];
    const float4 vx = *(const float4*)&VT[dv * S + 4 * tid];
    const int g = tid >> 4;
    const int r0 = (4 * tid) & 63;
    uT[r0 + 0][g] = kx.x * vx.x;
    uT[r0 + 1][g] = kx.y * vx.y;
    uT[r0 + 2][g] = kx.z * vx.z;
    uT[r0 + 3][g] = kx.w * vx.w;
  }
  __syncthreads();

  // ---- Phase A: s[n,g] = sum_r dA^{63-r} u[g,r]; then scale by 2CB ----
  {
    const int n = tid >> 2, q = tid & 3;   // q -> chunks 4q..4q+3
    float sre[4] = {0.f, 0.f, 0.f, 0.f}, sim[4] = {0.f, 0.f, 0.f, 0.f};
    for (int r = 0; r < 64; ++r) {
      const int row = 63 - r;
      const float prw = PowRe[row][n];
      const float piw = PowIm[row][n];
      const float4 u4 = *(const float4*)&uT[r][4 * q];
      sre[0] += prw * u4.x; sim[0] += piw * u4.x;
      sre[1] += prw * u4.y; sim[1] += piw * u4.y;
      sre[2] += prw * u4.z; sim[2] += piw * u4.z;
      sre[3] += prw * u4.w; sim[3] += piw * u4.w;
    }
    const float cbr = CB2[n][0], cbi = CB2[n][1];
#pragma unroll
    for (int p = 0; p < 4; ++p) {
      const int g = 4 * q + p;
      XL[g][n][0] = cbr * sre[p] - cbi * sim[p];
      XL[g][n][1] = cbr * sim[p] + cbi * sre[p];
    }
  }
  __syncthreads();

  // ---- Phase B (wave0): chunk-state scan; (wave1): kd; (wave2): zero pad ----
  if (tid < 64) {
    const int n = tid;
    const float dALr = PowRe[64][n], dALi = PowIm[64][n];
    float xr = 0.0f, xi = 0.0f;
    for (int g = 0; g < 16; ++g) {
      const float a = XL[g][n][0], b = XL[g][n][1];
      XL[g][n][0] = xr;   // 2CB * (state before chunk g)
      XL[g][n][1] = xi;
      const float nr = dALr * xr - dALi * xi + a;
      xi = dALr * xi + dALi * xr + b;
      xr = nr;
    }
  } else if (tid < 128) {
    const int dlt = tid - 64;
    float acc = 0.0f;
    for (int n = 0; n < 64; ++n)
      acc += CB2[n][0] * PowRe[dlt][n] - CB2[n][1] * PowIm[dlt][n];
    kd_ext[63 + dlt] = acc;
  } else if (tid < 191) {
    kd_ext[tid - 128] = 0.0f;
  }
  __syncthreads();

  // ---- Phase C: wave w -> chunks 4w..4w+3, lane r -> local time ----
  {
    const int w = tid >> 6, r = tid & 63;
    float yI[4] = {0.f, 0.f, 0.f, 0.f};
    for (int n = 0; n < 64; n += 2) {
      const float2 PR = *(const float2*)&PowRe[r + 1][n];
      const float2 PI = *(const float2*)&PowIm[r + 1][n];
#pragma unroll
      for (int p = 0; p < 4; ++p) {
        const float4 X4 = *(const float4*)&XL[4 * w + p][n][0];
        yI[p] += X4.x * PR.x - X4.y * PI.x + X4.z * PR.y - X4.w * PI.y;
      }
    }
    float yL[4] = {0.f, 0.f, 0.f, 0.f};
    for (int rp = 0; rp < 64; ++rp) {
      const float4 u4 = *(const float4*)&uT[rp][4 * w];
      const float kv = kd_ext[63 + r - rp];
      yL[0] += kv * u4.x;
      yL[1] += kv * u4.y;
      yL[2] += kv * u4.z;
      yL[3] += kv * u4.w;
    }
    const float dd = Dd[c];
#pragma unroll
    for (int p = 0; p < 4; ++p) {
      const int g = 4 * w + p;
      const int t = g * 64 + r;
      Y[t * CD + c] = yI[p] + yL[p] + dd * uT[r][g];
    }
  }
}

// ---------------- O[t, h*64+j] = sum_i Q[t,h*64+i] * Y[t, h*4096+i*64+j] ----
__global__ void contract_q(const float* __restrict__ Q, const float* __restrict__ Y,
                           float* __restrict__ O1) {
  const int t = blockIdx.x;
  const int tid = threadIdx.x;
  const int h = tid >> 6, j = tid & 63;
  const float* Yt = Y + t * CD + (h << 12) + j;
  const float* Qt = Q + t * D + (h << 6);
  float acc = 0.0f;
#pragma unroll 8
  for (int i = 0; i < 64; ++i) acc += Qt[i] * Yt[i << 6];
  O1[t * D + tid] = acc;
}

extern "C" void kernel_launch(void* const* d_in, const int* in_sizes, int n_in,
                              void* d_out, int out_size, void* d_ws, size_t ws_size,
                              hipStream_t stream) {
  const float* x   = (const float*)d_in[0];
  const float* WQ  = (const float*)d_in[1];
  const float* WK  = (const float*)d_in[2];
  const float* WV  = (const float*)d_in[3];
  const float* WO  = (const float*)d_in[4];
  const float* Cs  = (const float*)d_in[5];
  const float* Ds  = (const float*)d_in[6];
  const float* Are = (const float*)d_in[7];
  const float* Aim = (const float*)d_in[8];
  const float* Cre = (const float*)d_in[9];
  const float* Cim = (const float*)d_in[10];
  const float* Dd  = (const float*)d_in[11];
  float* out = (float*)d_out;

  float* ws   = (float*)d_ws;
  float* Q    = ws;             // S*D
  float* buf1 = Q + S * D;      // Kraw, then VT
  float* V    = buf1 + S * D;   // S*D
  float* Kn   = V + S * D;      // S*D
  float* buf4 = Kn + S * D;     // KnT, then O1
  float* Y    = buf4 + S * D;   // S*CD (t-major)

  dim3 ggrid(D / 64, S / 64);
  gemm_abT<<<ggrid, 256, 0, stream>>>(x, WQ, Q, S, D, D);
  gemm_abT<<<ggrid, 256, 0, stream>>>(x, WK, buf1, S, D, D);   // Kraw
  gemm_abT<<<ggrid, 256, 0, stream>>>(x, WV, V, S, D, D);
  shift_ssm<<<S, D, 0, stream>>>(buf1, Cs, Ds, Kn);
  dim3 tgrid(D / 32, S / 32);   // (16, 32)
  transpose_fp32<<<tgrid, 256, 0, stream>>>(Kn, buf4, S, D);   // KnT
  transpose_fp32<<<tgrid, 256, 0, stream>>>(V, buf1, S, D);    // VT
  s4d_chunked<<<CD, 256, 0, stream>>>(buf4, buf1, Are, Aim, Cre, Cim, Dd, Y);
  contract_q<<<S, D, 0, stream>>>(Q, Y, buf4);                 // O1 (reuses KnT)
  gemm_abT<<<ggrid, 256, 0, stream>>>(buf4, WO, out, S, D, D);
}

// Round 3
// 774.192 us; speedup vs baseline: 3.3428x; 1.1456x over previous
//
#include <hip/hip_runtime.h>

#define S 1024
#define D 512
#define HID 64
#define CD 32768
#define DT 0.1f

// ---------------- GEMM: C[m,n] = sum_k A[m*K+k] * B[n*K+k]  (C = A @ B^T) ----
__global__ __launch_bounds__(256) void gemm_abT(const float* __restrict__ A,
                                                const float* __restrict__ B,
                                                float* __restrict__ C,
                                                int M, int N, int K) {
  __shared__ float As[64][17];
  __shared__ float Bs[64][17];
  const int tx = threadIdx.x & 15;
  const int ty = threadIdx.x >> 4;
  const int m0 = blockIdx.y * 64, n0 = blockIdx.x * 64;
  float acc[4][4] = {};
  for (int k0 = 0; k0 < K; k0 += 16) {
#pragma unroll
    for (int r = 0; r < 4; ++r) {
      int row = ty + r * 16;
      As[row][tx] = A[(m0 + row) * K + k0 + tx];
      Bs[row][tx] = B[(n0 + row) * K + k0 + tx];
    }
    __syncthreads();
#pragma unroll
    for (int kk = 0; kk < 16; ++kk) {
      float a[4], b[4];
#pragma unroll
      for (int i = 0; i < 4; ++i) a[i] = As[ty * 4 + i][kk];
#pragma unroll
      for (int j = 0; j < 4; ++j) b[j] = Bs[tx * 4 + j][kk];
#pragma unroll
      for (int i = 0; i < 4; ++i)
#pragma unroll
        for (int j = 0; j < 4; ++j) acc[i][j] += a[i] * b[j];
    }
    __syncthreads();
  }
#pragma unroll
  for (int i = 0; i < 4; ++i)
#pragma unroll
    for (int j = 0; j < 4; ++j)
      C[(m0 + ty * 4 + i) * N + n0 + tx * 4 + j] = acc[i][j];
}

// ---------------- Shift SSM on K: 64-tap causal FIR + skip ------------------
// CsT is C_shift transposed: CsT[j][d], so tap reads are coalesced over d.
__global__ void shift_ssm(const float* __restrict__ Kin, const float* __restrict__ CsT,
                          const float* __restrict__ Ds, float* __restrict__ Kout) {
  const int t = blockIdx.x;
  const int d = threadIdx.x;
  float acc = Ds[d] * Kin[t * D + d];
  const int jmax = t < 63 ? t : 63;
  for (int j = 0; j <= jmax; ++j)
    acc += CsT[j * D + d] * Kin[(t - j) * D + d];
  Kout[t * D + d] = acc;
}

// ---------------- fp32 transpose: in[R][Cc] -> out[Cc][R] -------------------
__global__ __launch_bounds__(256) void transpose_fp32(const float* __restrict__ in,
                                                      float* __restrict__ out,
                                                      int R, int Cc) {
  __shared__ float tile[32][33];
  const int bx = blockIdx.x * 32;  // col base
  const int by = blockIdx.y * 32;  // row base
  const int lx = threadIdx.x & 31, ly = threadIdx.x >> 5;
#pragma unroll
  for (int m = 0; m < 32; m += 8)
    tile[ly + m][lx] = in[(by + ly + m) * Cc + bx + lx];
  __syncthreads();
#pragma unroll
  for (int m = 0; m < 32; m += 8)
    out[(bx + ly + m) * R + by + lx] = tile[lx][ly + m];
}

// ---------------- S4D diagonal SSM: chunked, one block per channel ----------
// 16 chunks of length 64. Phase A: chunk-local state sums via Pow table.
// Phase B: 16-step chunk-state scan (wave 0) + kd taps build (wave 1).
// Phase C: y = inter-chunk (states x dA^{r+1}) + intra-chunk conv (kd_ext).
// Y is written channel-major: Y[c*S + t]  (coalesced over lane r).
__global__ __launch_bounds__(256) void s4d_chunked(
    const float* __restrict__ KnT, const float* __restrict__ VT,
    const float* __restrict__ Are, const float* __restrict__ Aim,
    const float* __restrict__ Cre, const float* __restrict__ Cim,
    const float* __restrict__ Dd, float* __restrict__ Y) {
  __shared__ __align__(16) float PowRe[65][66];   // dA^k, k=0..64
  __shared__ __align__(16) float PowIm[65][66];
  __shared__ __align__(16) float uT[64][20];      // [r][g], pad->20
  __shared__ __align__(16) float XL[16][64][2];   // s' then 2CB*state-before-chunk
  __shared__ __align__(16) float CB2[64][2];      // 2*CB (complex)
  __shared__ __align__(16) float kd_ext[128];     // kd_ext[63+d]=kd[d]; [0..62]=0

  const int tid = threadIdx.x;
  const int c = blockIdx.x;
  const int dk = c >> 6;                           // h*64+i
  const int dv = ((c >> 12) << 6) | (c & 63);      // h*64+j

  // ---- setup: discretization, Pow table (dA^k), CB2, u ----
  {
    const int n = tid & 63, seg = tid >> 6;
    const float ar = Are[n], ai = Aim[n];
    const float den_re = 1.0f - 0.05f * ar;
    const float den_im = -0.05f * ai;
    const float num_re = 1.0f + 0.05f * ar;
    const float num_im = 0.05f * ai;
    const float inv_d2 = 1.0f / (den_re * den_re + den_im * den_im);
    const float dAr = (num_re * den_re + num_im * den_im) * inv_d2;
    const float dAi = (num_im * den_re - num_re * den_im) * inv_d2;
    float e2r = dAr * dAr - dAi * dAi, e2i = 2.0f * dAr * dAi;
    float e4r = e2r * e2r - e2i * e2i, e4i = 2.0f * e2r * e2i;
    float e8r = e4r * e4r - e4i * e4i, e8i = 2.0f * e4r * e4i;
    float e16r = e8r * e8r - e8i * e8i, e16i = 2.0f * e8r * e8i;
    float br = 1.0f, bi = 0.0f;
    for (int sgo = 0; sgo < seg; ++sgo) {
      float nr = br * e16r - bi * e16i;
      bi = br * e16i + bi * e16r;
      br = nr;
    }
    float pr = br, pi = bi;
    for (int k = 16 * seg + 1; k <= 16 * seg + 16; ++k) {
      float nr = pr * dAr - pi * dAi;
      pi = pr * dAi + pi * dAr;
      pr = nr;
      PowRe[k][n] = pr;
      PowIm[k][n] = pi;
    }
    if (seg == 0) {
      PowRe[0][n] = 1.0f;
      PowIm[0][n] = 0.0f;
      const float dBr = DT * den_re * inv_d2;
      const float dBi = -DT * den_im * inv_d2;
      const float cr = Cre[(c << 6) + n], ci = Cim[(c << 6) + n];
      CB2[n][0] = 2.0f * (cr * dBr - ci * dBi);
      CB2[n][1] = 2.0f * (cr * dBi + ci * dBr);
    }
    const float4 kx = *(const float4*)&KnT[dk * S + 4 * tid];
    const float4 vx = *(const float4*)&VT[dv * S + 4 * tid];
    const int g = tid >> 4;
    const int r0 = (4 * tid) & 63;
    uT[r0 + 0][g] = kx.x * vx.x;
    uT[r0 + 1][g] = kx.y * vx.y;
    uT[r0 + 2][g] = kx.z * vx.z;
    uT[r0 + 3][g] = kx.w * vx.w;
  }
  __syncthreads();

  // ---- Phase A: s[n,g] = sum_r dA^{63-r} u[g,r]; then scale by 2CB ----
  {
    const int n = tid >> 2, q = tid & 3;   // q -> chunks 4q..4q+3
    float sre[4] = {0.f, 0.f, 0.f, 0.f}, sim[4] = {0.f, 0.f, 0.f, 0.f};
    for (int r = 0; r < 64; ++r) {
      const int row = 63 - r;
      const float prw = PowRe[row][n];
      const float piw = PowIm[row][n];
      const float4 u4 = *(const float4*)&uT[r][4 * q];
      sre[0] += prw * u4.x; sim[0] += piw * u4.x;
      sre[1] += prw * u4.y; sim[1] += piw * u4.y;
      sre[2] += prw * u4.z; sim[2] += piw * u4.z;
      sre[3] += prw * u4.w; sim[3] += piw * u4.w;
    }
    const float cbr = CB2[n][0], cbi = CB2[n][1];
#pragma unroll
    for (int p = 0; p < 4; ++p) {
      const int g = 4 * q + p;
      XL[g][n][0] = cbr * sre[p] - cbi * sim[p];
      XL[g][n][1] = cbr * sim[p] + cbi * sre[p];
    }
  }
  __syncthreads();

  // ---- Phase B (wave0): chunk-state scan; (wave1): kd; (wave2): zero pad ----
  if (tid < 64) {
    const int n = tid;
    const float dALr = PowRe[64][n], dALi = PowIm[64][n];
    float xr = 0.0f, xi = 0.0f;
    for (int g = 0; g < 16; ++g) {
      const float a = XL[g][n][0], b = XL[g][n][1];
      XL[g][n][0] = xr;
      XL[g][n][1] = xi;
      const float nr = dALr * xr - dALi * xi + a;
      xi = dALr * xi + dALi * xr + b;
      xr = nr;
    }
  } else if (tid < 128) {
    const int dlt = tid - 64;
    float acc = 0.0f;
    for (int n = 0; n < 64; ++n)
      acc += CB2[n][0] * PowRe[dlt][n] - CB2[n][1] * PowIm[dlt][n];
    kd_ext[63 + dlt] = acc;
  } else if (tid < 191) {
    kd_ext[tid - 128] = 0.0f;
  }
  __syncthreads();

  // ---- Phase C: wave w -> chunks 4w..4w+3, lane r -> local time ----
  {
    const int w = tid >> 6, r = tid & 63;
    float yI[4] = {0.f, 0.f, 0.f, 0.f};
    for (int n = 0; n < 64; n += 2) {
      const float2 PR = *(const float2*)&PowRe[r + 1][n];
      const float2 PI = *(const float2*)&PowIm[r + 1][n];
#pragma unroll
      for (int p = 0; p < 4; ++p) {
        const float4 X4 = *(const float4*)&XL[4 * w + p][n][0];
        yI[p] += X4.x * PR.x - X4.y * PI.x + X4.z * PR.y - X4.w * PI.y;
      }
    }
    float yL[4] = {0.f, 0.f, 0.f, 0.f};
    for (int rp = 0; rp < 64; ++rp) {
      const float4 u4 = *(const float4*)&uT[rp][4 * w];
      const float kv = kd_ext[63 + r - rp];
      yL[0] += kv * u4.x;
      yL[1] += kv * u4.y;
      yL[2] += kv * u4.z;
      yL[3] += kv * u4.w;
    }
    const float dd = Dd[c];
#pragma unroll
    for (int p = 0; p < 4; ++p) {
      const int g = 4 * w + p;
      Y[c * S + g * 64 + r] = yI[p] + yL[p] + dd * uT[r][g];
    }
  }
}

// ------ O1[t, h*64+j] = sum_i Q[t,h*64+i] * Y[(h*4096+i*64+j)*S + t] --------
__global__ __launch_bounds__(256) void contract_qT(const float* __restrict__ Q,
                                                   const float* __restrict__ Y,
                                                   float* __restrict__ O1) {
  __shared__ float Qs[64][65];
  __shared__ float Os[64][17];
  const int jb = blockIdx.x;       // 0..3 -> 16 j's
  const int h  = blockIdx.y;       // 0..7
  const int t0 = blockIdx.z * 64;  // t tile
  const int tid = threadIdx.x;
#pragma unroll
  for (int m = 0; m < 16; ++m) {
    const int idx = tid + m * 256;
    const int tt = idx >> 6, i = idx & 63;
    Qs[tt][i] = Q[(t0 + tt) * D + (h << 6) + i];
  }
  __syncthreads();
  const int tl = tid & 63, jg = tid >> 6;
  const int jbase = jb * 16 + jg * 4;
  float acc[4] = {0.f, 0.f, 0.f, 0.f};
  const float* Ybase = Y + ((h << 12) + jbase) * S + t0 + tl;
  for (int i = 0; i < 64; ++i) {
    const float qv = Qs[tl][i];
    const float* Yr = Ybase + (i << 6) * S;
#pragma unroll
    for (int jj = 0; jj < 4; ++jj) acc[jj] += qv * Yr[jj * S];
  }
#pragma unroll
  for (int jj = 0; jj < 4; ++jj) Os[tl][jg * 4 + jj] = acc[jj];
  __syncthreads();
#pragma unroll
  for (int m = 0; m < 4; ++m) {
    const int row = (tid >> 4) + m * 16;
    const int col = tid & 15;
    O1[(t0 + row) * D + (h << 6) + jb * 16 + col] = Os[row][col];
  }
}

extern "C" void kernel_launch(void* const* d_in, const int* in_sizes, int n_in,
                              void* d_out, int out_size, void* d_ws, size_t ws_size,
                              hipStream_t stream) {
  const float* x   = (const float*)d_in[0];
  const float* WQ  = (const float*)d_in[1];
  const float* WK  = (const float*)d_in[2];
  const float* WV  = (const float*)d_in[3];
  const float* WO  = (const float*)d_in[4];
  const float* Cs  = (const float*)d_in[5];
  const float* Ds  = (const float*)d_in[6];
  const float* Are = (const float*)d_in[7];
  const float* Aim = (const float*)d_in[8];
  const float* Cre = (const float*)d_in[9];
  const float* Cim = (const float*)d_in[10];
  const float* Dd  = (const float*)d_in[11];
  float* out = (float*)d_out;

  float* ws   = (float*)d_ws;
  float* Q    = ws;             // S*D
  float* buf1 = Q + S * D;      // Kraw, then VT
  float* V    = buf1 + S * D;   // S*D
  float* Kn   = V + S * D;      // S*D
  float* buf4 = Kn + S * D;     // KnT, then O1
  float* CsT  = buf4 + S * D;   // HID*D
  float* Y    = CsT + HID * D;  // CD*S (channel-major)

  dim3 ggrid(D / 64, S / 64);
  gemm_abT<<<ggrid, 256, 0, stream>>>(x, WQ, Q, S, D, D);
  gemm_abT<<<ggrid, 256, 0, stream>>>(x, WK, buf1, S, D, D);   // Kraw
  gemm_abT<<<ggrid, 256, 0, stream>>>(x, WV, V, S, D, D);
  dim3 cst_grid(HID / 32, D / 32);  // Cs[512][64] -> CsT[64][512]
  transpose_fp32<<<cst_grid, 256, 0, stream>>>(Cs, CsT, D, HID);
  shift_ssm<<<S, D, 0, stream>>>(buf1, CsT, Ds, Kn);
  dim3 tgrid(D / 32, S / 32);
  transpose_fp32<<<tgrid, 256, 0, stream>>>(Kn, buf4, S, D);   // KnT
  transpose_fp32<<<tgrid, 256, 0, stream>>>(V, buf1, S, D);    // VT
  s4d_chunked<<<CD, 256, 0, stream>>>(buf4, buf1, Are, Aim, Cre, Cim, Dd, Y);
  dim3 cgrid(4, 8, S / 64);
  contract_qT<<<cgrid, 256, 0, stream>>>(Q, Y, buf4);          // O1
  gemm_abT<<<ggrid, 256, 0, stream>>>(buf4, WO, out, S, D, D);
}

// Round 4
// 569.179 us; speedup vs baseline: 4.5469x; 1.3602x over previous
//
#include <hip/hip_runtime.h>

#define S 1024
#define D 512
#define HID 64
#define CD 32768
#define DT 0.1f

typedef __attribute__((ext_vector_type(4))) float floatx4;
typedef __attribute__((ext_vector_type(8))) short shortx8;

__device__ __forceinline__ unsigned short f2bf(float f) {
  union { float f; unsigned int u; } v;
  v.f = f;
  unsigned int r = v.u + 0x7FFFu + ((v.u >> 16) & 1u);
  return (unsigned short)(r >> 16);
}
__device__ __forceinline__ float bf2f(unsigned short h) {
  union { unsigned int u; float f; } v;
  v.u = ((unsigned int)h) << 16;
  return v.f;
}

// ---------------- GEMM: C[m,n] = sum_k A[m*K+k] * B[n*K+k]  (C = A @ B^T) ----
__global__ __launch_bounds__(256) void gemm_abT(const float* __restrict__ A,
                                                const float* __restrict__ B,
                                                float* __restrict__ C,
                                                int M, int N, int K) {
  __shared__ float As[64][17];
  __shared__ float Bs[64][17];
  const int tx = threadIdx.x & 15;
  const int ty = threadIdx.x >> 4;
  const int m0 = blockIdx.y * 64, n0 = blockIdx.x * 64;
  float acc[4][4] = {};
  for (int k0 = 0; k0 < K; k0 += 16) {
#pragma unroll
    for (int r = 0; r < 4; ++r) {
      int row = ty + r * 16;
      As[row][tx] = A[(m0 + row) * K + k0 + tx];
      Bs[row][tx] = B[(n0 + row) * K + k0 + tx];
    }
    __syncthreads();
#pragma unroll
    for (int kk = 0; kk < 16; ++kk) {
      float a[4], b[4];
#pragma unroll
      for (int i = 0; i < 4; ++i) a[i] = As[ty * 4 + i][kk];
#pragma unroll
      for (int j = 0; j < 4; ++j) b[j] = Bs[tx * 4 + j][kk];
#pragma unroll
      for (int i = 0; i < 4; ++i)
#pragma unroll
        for (int j = 0; j < 4; ++j) acc[i][j] += a[i] * b[j];
    }
    __syncthreads();
  }
#pragma unroll
  for (int i = 0; i < 4; ++i)
#pragma unroll
    for (int j = 0; j < 4; ++j)
      C[(m0 + ty * 4 + i) * N + n0 + tx * 4 + j] = acc[i][j];
}

// ---------------- Shift SSM on K: 64-tap causal FIR + skip ------------------
__global__ void shift_ssm(const float* __restrict__ Kin, const float* __restrict__ CsT,
                          const float* __restrict__ Ds, float* __restrict__ Kout) {
  const int t = blockIdx.x;
  const int d = threadIdx.x;
  float acc = Ds[d] * Kin[t * D + d];
  const int jmax = t < 63 ? t : 63;
  for (int j = 0; j <= jmax; ++j)
    acc += CsT[j * D + d] * Kin[(t - j) * D + d];
  Kout[t * D + d] = acc;
}

// ---------------- fp32 transpose: in[R][Cc] -> out[Cc][R] -------------------
__global__ __launch_bounds__(256) void transpose_fp32(const float* __restrict__ in,
                                                      float* __restrict__ out,
                                                      int R, int Cc) {
  __shared__ float tile[32][33];
  const int bx = blockIdx.x * 32;
  const int by = blockIdx.y * 32;
  const int lx = threadIdx.x & 31, ly = threadIdx.x >> 5;
#pragma unroll
  for (int m = 0; m < 32; m += 8)
    tile[ly + m][lx] = in[(by + ly + m) * Cc + bx + lx];
  __syncthreads();
#pragma unroll
  for (int m = 0; m < 32; m += 8)
    out[(bx + ly + m) * R + by + lx] = tile[lx][ly + m];
}

// ---------------- S4D diagonal SSM via MFMA, one block per channel ----------
// Phase A (MFMA): s[n,g] = sum_r Pow[63-r][n] * u[r,g]  (complex, K=64)
// Scan (wave0):   16-step chunk-state recurrence with fp32 dA^64
// kd (all):       kd[dlt] = sum_n CB2 . Pow[dlt]  (128-dot, 4 lanes/dlt)
// Phase C (MFMA): y = PCc(64x128) @ Xc^T  +  Toeplitz(kd) @ U^T, then +dd*u
__global__ __launch_bounds__(256) void s4d_mfma(
    const float* __restrict__ KnT, const float* __restrict__ VT,
    const float* __restrict__ Are, const float* __restrict__ Aim,
    const float* __restrict__ Cre, const float* __restrict__ Cim,
    const float* __restrict__ Dd, float* __restrict__ Y) {
  __shared__ __align__(16) unsigned short PAre[64][72];  // [n][r] = Pow[63-r][n]
  __shared__ __align__(16) unsigned short PAim[64][72];
  __shared__ __align__(16) unsigned short PCc[64][136];  // [r][n]=Pow[r+1].re, [r][64+n]=-Pow[r+1].im
  __shared__ __align__(16) unsigned short Ub[16][72];    // [g][r] = u
  __shared__ __align__(16) unsigned short Tb[64][72];    // Toeplitz kd
  __shared__ __align__(16) unsigned short Xc[16][136];   // [g][n]=X.re, [g][64+n]=X.im
  __shared__ __align__(16) float SLf[16][132];           // phase-A out, then y out
  __shared__ float CB2[64][2];
  __shared__ __align__(16) float cb2ext[128];
  __shared__ float dA64re[64], dA64im[64];
  __shared__ unsigned short kdext[136];                  // [63+d]=kd[d], [0..62]=0

  const int tid = threadIdx.x;
  const int c = blockIdx.x;
  const int dk = c >> 6;
  const int dv = ((c >> 12) << 6) | (c & 63);
  const int lane = tid & 63;
  const int w = tid >> 6;

  // ---- region 1: discretization, bf16 power tables, CB2, U ----
  {
    const int n = lane, seg = w;
    const float ar = Are[n], ai = Aim[n];
    const float den_re = 1.0f - 0.05f * ar;
    const float den_im = -0.05f * ai;
    const float num_re = 1.0f + 0.05f * ar;
    const float num_im = 0.05f * ai;
    const float inv_d2 = 1.0f / (den_re * den_re + den_im * den_im);
    const float dAr = (num_re * den_re + num_im * den_im) * inv_d2;
    const float dAi = (num_im * den_re - num_re * den_im) * inv_d2;
    float e2r = dAr * dAr - dAi * dAi, e2i = 2.0f * dAr * dAi;
    float e4r = e2r * e2r - e2i * e2i, e4i = 2.0f * e2r * e2i;
    float e8r = e4r * e4r - e4i * e4i, e8i = 2.0f * e4r * e4i;
    float e16r = e8r * e8r - e8i * e8i, e16i = 2.0f * e8r * e8i;
    float br = 1.0f, bi = 0.0f;
    for (int sgo = 0; sgo < seg; ++sgo) {
      float nr = br * e16r - bi * e16i;
      bi = br * e16i + bi * e16r;
      br = nr;
    }
    float pr = br, pi = bi;
    for (int k = 16 * seg + 1; k <= 16 * seg + 16; ++k) {
      float nr = pr * dAr - pi * dAi;
      pi = pr * dAi + pi * dAr;
      pr = nr;
      if (k <= 63) {
        PAre[n][63 - k] = f2bf(pr);
        PAim[n][63 - k] = f2bf(pi);
      }
      PCc[k - 1][n] = f2bf(pr);
      PCc[k - 1][64 + n] = f2bf(-pi);
      if (k == 64) {
        dA64re[n] = pr;
        dA64im[n] = pi;
      }
    }
    if (seg == 0) {
      PAre[n][63] = f2bf(1.0f);
      PAim[n][63] = 0;
      const float dBr = DT * den_re * inv_d2;
      const float dBi = -DT * den_im * inv_d2;
      const float cr = Cre[(c << 6) + n], ci = Cim[(c << 6) + n];
      const float c2r = 2.0f * (cr * dBr - ci * dBi);
      const float c2i = 2.0f * (cr * dBi + ci * dBr);
      CB2[n][0] = c2r;
      CB2[n][1] = c2i;
      cb2ext[n] = c2r;
      cb2ext[64 + n] = c2i;
    }
    if (tid < 63) kdext[tid] = 0;
    if (tid == 63) kdext[127] = 0;
    const float4 kx = *(const float4*)&KnT[dk * S + 4 * tid];
    const float4 vx = *(const float4*)&VT[dv * S + 4 * tid];
    const int g = tid >> 4;
    const int r0 = (4 * tid) & 63;
    Ub[g][r0 + 0] = f2bf(kx.x * vx.x);
    Ub[g][r0 + 1] = f2bf(kx.y * vx.y);
    Ub[g][r0 + 2] = f2bf(kx.z * vx.z);
    Ub[g][r0 + 3] = f2bf(kx.w * vx.w);
  }
  __syncthreads();

  // ---- region 2: phase A MFMA (+ CB2 scale -> SLf) and kd taps ----
  {
    const int row = lane & 15, quad = lane >> 4;
    const shortx8 b0 = *(const shortx8*)&Ub[row][quad * 8];
    const shortx8 b1 = *(const shortx8*)&Ub[row][32 + quad * 8];
    const int n0 = 16 * w;
    const shortx8 ar0 = *(const shortx8*)&PAre[n0 + row][quad * 8];
    const shortx8 ar1 = *(const shortx8*)&PAre[n0 + row][32 + quad * 8];
    const shortx8 ai0 = *(const shortx8*)&PAim[n0 + row][quad * 8];
    const shortx8 ai1 = *(const shortx8*)&PAim[n0 + row][32 + quad * 8];
    floatx4 sre = {0.f, 0.f, 0.f, 0.f}, sim = {0.f, 0.f, 0.f, 0.f};
    sre = __builtin_amdgcn_mfma_f32_16x16x32_bf16(ar0, b0, sre, 0, 0, 0);
    sre = __builtin_amdgcn_mfma_f32_16x16x32_bf16(ar1, b1, sre, 0, 0, 0);
    sim = __builtin_amdgcn_mfma_f32_16x16x32_bf16(ai0, b0, sim, 0, 0, 0);
    sim = __builtin_amdgcn_mfma_f32_16x16x32_bf16(ai1, b1, sim, 0, 0, 0);
    const int g = row;
#pragma unroll
    for (int v = 0; v < 4; ++v) {
      const int n = n0 + quad * 4 + v;
      const float cbr = CB2[n][0], cbi = CB2[n][1];
      float2 xv;
      xv.x = cbr * sre[v] - cbi * sim[v];
      xv.y = cbr * sim[v] + cbi * sre[v];
      *(float2*)&SLf[g][2 * n] = xv;
    }
  }
  {
    const int dlt = tid >> 2, p = tid & 3;
    float acc = 0.0f;
    if (dlt == 0) {
      for (int n = 16 * p; n < 16 * p + 16; ++n) acc += cb2ext[n];
    } else {
      const int prow = dlt - 1;
#pragma unroll
      for (int jj = 0; jj < 4; ++jj) {
        const int k = 32 * p + 8 * jj;
        const shortx8 pk = *(const shortx8*)&PCc[prow][k];
        const float4 ca = *(const float4*)&cb2ext[k];
        const float4 cb = *(const float4*)&cb2ext[k + 4];
        acc += bf2f((unsigned short)pk[0]) * ca.x;
        acc += bf2f((unsigned short)pk[1]) * ca.y;
        acc += bf2f((unsigned short)pk[2]) * ca.z;
        acc += bf2f((unsigned short)pk[3]) * ca.w;
        acc += bf2f((unsigned short)pk[4]) * cb.x;
        acc += bf2f((unsigned short)pk[5]) * cb.y;
        acc += bf2f((unsigned short)pk[6]) * cb.z;
        acc += bf2f((unsigned short)pk[7]) * cb.w;
      }
    }
    acc += __shfl_xor(acc, 1, 64);
    acc += __shfl_xor(acc, 2, 64);
    if (p == 0) kdext[63 + dlt] = f2bf(acc);
  }
  __syncthreads();

  // ---- region 3: wave0 chunk scan -> Xc;  waves1-3 Toeplitz build ----
  if (w == 0) {
    const int n = lane;
    const float er = dA64re[n], ei = dA64im[n];
    float xr = 0.0f, xi = 0.0f;
    for (int g = 0; g < 16; ++g) {
      const float2 ab = *(const float2*)&SLf[g][2 * n];
      Xc[g][n] = f2bf(xr);
      Xc[g][64 + n] = f2bf(xi);
      const float nr = er * xr - ei * xi + ab.x;
      xi = er * xi + ei * xr + ab.y;
      xr = nr;
    }
  } else {
    for (int e = (w - 1) * 64 + lane; e < 4096; e += 192) {
      const int r = e >> 6, rp = e & 63;
      Tb[r][rp] = kdext[63 + r - rp];
    }
  }
  __syncthreads();

  // ---- region 4: phase C MFMA (inter K=128 + local K=64) -> SLf[g][r] ----
  {
    const int row = lane & 15, quad = lane >> 4;
    const int r0 = 16 * w;
    floatx4 acc = {0.f, 0.f, 0.f, 0.f};
#pragma unroll
    for (int i = 0; i < 4; ++i) {
      const shortx8 a = *(const shortx8*)&PCc[r0 + row][32 * i + quad * 8];
      const shortx8 b = *(const shortx8*)&Xc[row][32 * i + quad * 8];
      acc = __builtin_amdgcn_mfma_f32_16x16x32_bf16(a, b, acc, 0, 0, 0);
    }
#pragma unroll
    for (int i = 0; i < 2; ++i) {
      const shortx8 a = *(const shortx8*)&Tb[r0 + row][32 * i + quad * 8];
      const shortx8 b = *(const shortx8*)&Ub[row][32 * i + quad * 8];
      acc = __builtin_amdgcn_mfma_f32_16x16x32_bf16(a, b, acc, 0, 0, 0);
    }
    const float dd = Dd[c];
    const int g = row;
#pragma unroll
    for (int v = 0; v < 4; ++v) {
      const int r = r0 + quad * 4 + v;
      SLf[g][r] = acc[v] + dd * bf2f(Ub[g][r]);
    }
  }
  __syncthreads();

  // ---- region 5: coalesced Y store (channel-major) ----
  {
    const int t = 4 * tid;
    const int g = t >> 6, r = t & 63;
    const float4 y4 = *(const float4*)&SLf[g][r];
    *(float4*)&Y[c * S + t] = y4;
  }
}

// ------ O1[t, h*64+j] = sum_i Q[t,h*64+i] * Y[(h*4096+i*64+j)*S + t] --------
__global__ __launch_bounds__(256) void contract_qT(const float* __restrict__ Q,
                                                   const float* __restrict__ Y,
                                                   float* __restrict__ O1) {
  __shared__ float Qs[64][65];
  __shared__ float Os[64][17];
  const int jb = blockIdx.x;
  const int h  = blockIdx.y;
  const int t0 = blockIdx.z * 64;
  const int tid = threadIdx.x;
#pragma unroll
  for (int m = 0; m < 16; ++m) {
    const int idx = tid + m * 256;
    const int tt = idx >> 6, i = idx & 63;
    Qs[tt][i] = Q[(t0 + tt) * D + (h << 6) + i];
  }
  __syncthreads();
  const int tl = tid & 63, jg = tid >> 6;
  const int jbase = jb * 16 + jg * 4;
  float acc[4] = {0.f, 0.f, 0.f, 0.f};
  const float* Ybase = Y + ((h << 12) + jbase) * S + t0 + tl;
  for (int i = 0; i < 64; ++i) {
    const float qv = Qs[tl][i];
    const float* Yr = Ybase + (i << 6) * S;
#pragma unroll
    for (int jj = 0; jj < 4; ++jj) acc[jj] += qv * Yr[jj * S];
  }
#pragma unroll
  for (int jj = 0; jj < 4; ++jj) Os[tl][jg * 4 + jj] = acc[jj];
  __syncthreads();
#pragma unroll
  for (int m = 0; m < 4; ++m) {
    const int row = (tid >> 4) + m * 16;
    const int col = tid & 15;
    O1[(t0 + row) * D + (h << 6) + jb * 16 + col] = Os[row][col];
  }
}

extern "C" void kernel_launch(void* const* d_in, const int* in_sizes, int n_in,
                              void* d_out, int out_size, void* d_ws, size_t ws_size,
                              hipStream_t stream) {
  const float* x   = (const float*)d_in[0];
  const float* WQ  = (const float*)d_in[1];
  const float* WK  = (const float*)d_in[2];
  const float* WV  = (const float*)d_in[3];
  const float* WO  = (const float*)d_in[4];
  const float* Cs  = (const float*)d_in[5];
  const float* Ds  = (const float*)d_in[6];
  const float* Are = (const float*)d_in[7];
  const float* Aim = (const float*)d_in[8];
  const float* Cre = (const float*)d_in[9];
  const float* Cim = (const float*)d_in[10];
  const float* Dd  = (const float*)d_in[11];
  float* out = (float*)d_out;

  float* ws   = (float*)d_ws;
  float* Q    = ws;             // S*D
  float* buf1 = Q + S * D;      // Kraw, then VT
  float* V    = buf1 + S * D;   // S*D
  float* Kn   = V + S * D;      // S*D
  float* buf4 = Kn + S * D;     // KnT, then O1
  float* CsT  = buf4 + S * D;   // HID*D
  float* Y    = CsT + HID * D;  // CD*S (channel-major)

  dim3 ggrid(D / 64, S / 64);
  gemm_abT<<<ggrid, 256, 0, stream>>>(x, WQ, Q, S, D, D);
  gemm_abT<<<ggrid, 256, 0, stream>>>(x, WK, buf1, S, D, D);   // Kraw
  gemm_abT<<<ggrid, 256, 0, stream>>>(x, WV, V, S, D, D);
  dim3 cst_grid(HID / 32, D / 32);
  transpose_fp32<<<cst_grid, 256, 0, stream>>>(Cs, CsT, D, HID);
  shift_ssm<<<S, D, 0, stream>>>(buf1, CsT, Ds, Kn);
  dim3 tgrid(D / 32, S / 32);
  transpose_fp32<<<tgrid, 256, 0, stream>>>(Kn, buf4, S, D);   // KnT
  transpose_fp32<<<tgrid, 256, 0, stream>>>(V, buf1, S, D);    // VT
  s4d_mfma<<<CD, 256, 0, stream>>>(buf4, buf1, Are, Aim, Cre, Cim, Dd, Y);
  dim3 cgrid(4, 8, S / 64);
  contract_qT<<<cgrid, 256, 0, stream>>>(Q, Y, buf4);          // O1
  gemm_abT<<<ggrid, 256, 0, stream>>>(buf4, WO, out, S, D, D);
}

// Round 6
// 390.574 us; speedup vs baseline: 6.6261x; 1.4573x over previous
//
#include <hip/hip_runtime.h>

#define S 1024
#define D 512
#define HID 64
#define CD 32768
#define DT 0.1f

typedef __attribute__((ext_vector_type(4))) float floatx4;
typedef __attribute__((ext_vector_type(8))) short shortx8;
// may_alias variants for type-punned LDS/global access (TBAA-safe)
typedef short shortx8_a __attribute__((ext_vector_type(8), may_alias));
typedef unsigned int uint_a __attribute__((may_alias));
typedef unsigned int uint2_a __attribute__((ext_vector_type(2), may_alias));
typedef float float4_a __attribute__((ext_vector_type(4), may_alias));
typedef float float_a __attribute__((may_alias));

__device__ __forceinline__ unsigned short f2bf(float f) {
  union { float f; unsigned int u; } v;
  v.f = f;
  unsigned int r = v.u + 0x7FFFu + ((v.u >> 16) & 1u);
  return (unsigned short)(r >> 16);
}
__device__ __forceinline__ float bf2f(unsigned short h) {
  union { unsigned int u; float f; } v;
  v.u = ((unsigned int)h) << 16;
  return v.f;
}

// ---------------- GEMM: C[m,n] = sum_k A[m*K+k] * B[n*K+k] ------------------
__global__ __launch_bounds__(256) void gemm_abT(const float* __restrict__ A,
                                                const float* __restrict__ B,
                                                float* __restrict__ C,
                                                int M, int N, int K) {
  __shared__ float As[64][17];
  __shared__ float Bs[64][17];
  const int tx = threadIdx.x & 15;
  const int ty = threadIdx.x >> 4;
  const int m0 = blockIdx.y * 64, n0 = blockIdx.x * 64;
  float acc[4][4] = {};
  for (int k0 = 0; k0 < K; k0 += 16) {
#pragma unroll
    for (int r = 0; r < 4; ++r) {
      int row = ty + r * 16;
      As[row][tx] = A[(m0 + row) * K + k0 + tx];
      Bs[row][tx] = B[(n0 + row) * K + k0 + tx];
    }
    __syncthreads();
#pragma unroll
    for (int kk = 0; kk < 16; ++kk) {
      float a[4], b[4];
#pragma unroll
      for (int i = 0; i < 4; ++i) a[i] = As[ty * 4 + i][kk];
#pragma unroll
      for (int j = 0; j < 4; ++j) b[j] = Bs[tx * 4 + j][kk];
#pragma unroll
      for (int i = 0; i < 4; ++i)
#pragma unroll
        for (int j = 0; j < 4; ++j) acc[i][j] += a[i] * b[j];
    }
    __syncthreads();
  }
#pragma unroll
  for (int i = 0; i < 4; ++i)
#pragma unroll
    for (int j = 0; j < 4; ++j)
      C[(m0 + ty * 4 + i) * N + n0 + tx * 4 + j] = acc[i][j];
}

// ---------------- Shift SSM on K ------------------------------------------
__global__ void shift_ssm(const float* __restrict__ Kin, const float* __restrict__ CsT,
                          const float* __restrict__ Ds, float* __restrict__ Kout) {
  const int t = blockIdx.x;
  const int d = threadIdx.x;
  float acc = Ds[d] * Kin[t * D + d];
  const int jmax = t < 63 ? t : 63;
  for (int j = 0; j <= jmax; ++j)
    acc += CsT[j * D + d] * Kin[(t - j) * D + d];
  Kout[t * D + d] = acc;
}

// ---------------- fp32 transpose: in[R][Cc] -> out[Cc][R] -------------------
__global__ __launch_bounds__(256) void transpose_fp32(const float* __restrict__ in,
                                                      float* __restrict__ out,
                                                      int R, int Cc) {
  __shared__ float tile[32][33];
  const int bx = blockIdx.x * 32;
  const int by = blockIdx.y * 32;
  const int lx = threadIdx.x & 31, ly = threadIdx.x >> 5;
#pragma unroll
  for (int m = 0; m < 32; m += 8)
    tile[ly + m][lx] = in[(by + ly + m) * Cc + bx + lx];
  __syncthreads();
#pragma unroll
  for (int m = 0; m < 32; m += 8)
    out[(bx + ly + m) * R + by + lx] = tile[lx][ly + m];
}

// ---------------- prep_tables: shared dA-power tables (1 block) -------------
__global__ void prep_tables(const float* __restrict__ Are, const float* __restrict__ Aim,
                            unsigned short* __restrict__ TABG,
                            unsigned short* __restrict__ PCc2g) {
  const int n = threadIdx.x;  // 64 threads
  unsigned short* PAre = TABG;
  unsigned short* PAim = TABG + 4608;
  unsigned short* PCc  = TABG + 9216;
  float_a* dA64 = (float_a*)(TABG + 17920);
  const float ar = Are[n], ai = Aim[n];
  const float den_re = 1.0f - 0.05f * ar;
  const float den_im = -0.05f * ai;
  const float num_re = 1.0f + 0.05f * ar;
  const float num_im = 0.05f * ai;
  const float inv_d2 = 1.0f / (den_re * den_re + den_im * den_im);
  const float dAr = (num_re * den_re + num_im * den_im) * inv_d2;
  const float dAi = (num_im * den_re - num_re * den_im) * inv_d2;
  PAre[n * 72 + 63] = f2bf(1.0f);
  PAim[n * 72 + 63] = 0;
  PCc2g[n] = f2bf(1.0f);
  PCc2g[64 + n] = 0;
  float pr = 1.0f, pi = 0.0f;
  for (int k = 1; k <= 64; ++k) {
    const float nr = pr * dAr - pi * dAi;
    pi = pr * dAi + pi * dAr;
    pr = nr;
    if (k <= 63) {
      PAre[n * 72 + 63 - k] = f2bf(pr);
      PAim[n * 72 + 63 - k] = f2bf(pi);
      PCc2g[k * 136 + n] = f2bf(pr);
      PCc2g[k * 136 + 64 + n] = f2bf(-pi);
    }
    PCc[(k - 1) * 136 + n] = f2bf(pr);
    PCc[(k - 1) * 136 + 64 + n] = f2bf(-pi);
    if (k == 64) { dA64[2 * n] = pr; dA64[2 * n + 1] = pi; }
  }
}

// ---------------- prep_cb: cb2pack[c][128] = bf16(2*C*dB) re|im -------------
__global__ __launch_bounds__(256) void prep_cb(const float* __restrict__ Are,
                                               const float* __restrict__ Aim,
                                               const float* __restrict__ Cre,
                                               const float* __restrict__ Cim,
                                               unsigned short* __restrict__ cb2pack) {
  const int gid = blockIdx.x * 256 + threadIdx.x;
  const int c = gid >> 6, n = gid & 63;
  const float ar = Are[n], ai = Aim[n];
  const float den_re = 1.0f - 0.05f * ar;
  const float den_im = -0.05f * ai;
  const float inv_d2 = 1.0f / (den_re * den_re + den_im * den_im);
  const float dBr = DT * den_re * inv_d2;
  const float dBi = -DT * den_im * inv_d2;
  const float cr = Cre[gid], ci = Cim[gid];
  cb2pack[c * 128 + n] = f2bf(2.0f * (cr * dBr - ci * dBi));
  cb2pack[c * 128 + 64 + n] = f2bf(2.0f * (cr * dBi + ci * dBr));
}

// ---------------- prep_kd: kd GEMM -> kdpack[c][128] in kdR layout ----------
// kdR[m] = kd[64-m] for m in [1,64], else 0
__global__ __launch_bounds__(256) void prep_kd(const unsigned short* __restrict__ cb2pack,
                                               const unsigned short* __restrict__ PCc2g,
                                               unsigned short* __restrict__ kdpack) {
  const int c0 = blockIdx.x << 4;
  const int tid = threadIdx.x, l = tid & 63, w = tid >> 6;
  const int l15 = l & 15, q = l >> 4;
  floatx4 acc = {0.f, 0.f, 0.f, 0.f};
#pragma unroll
  for (int k = 0; k < 4; ++k) {
    const shortx8 a = *(const shortx8_a*)&cb2pack[(c0 + l15) * 128 + 8 * q + 32 * k];
    const shortx8 b = *(const shortx8_a*)&PCc2g[(16 * w + l15) * 136 + 8 * q + 32 * k];
    acc = __builtin_amdgcn_mfma_f32_16x16x32_bf16(a, b, acc, 0, 0, 0);
  }
  const int dlt = 16 * w + l15;
#pragma unroll
  for (int v = 0; v < 4; ++v)
    kdpack[(c0 + 4 * q + v) * 128 + 64 - dlt] = f2bf(acc[v]);
  const int row = tid >> 4, p = tid & 15;
#pragma unroll
  for (int k2 = 0; k2 < 4; ++k2) {
    const int idx = p + 16 * k2;
    const int m = (idx == 0) ? 0 : 64 + idx;
    kdpack[(c0 + row) * 128 + m] = 0;
  }
}

// ---------------- s4d_fused: diagonal SSM + Q-contraction -------------------
// Block = (h, j): wave w handles channels i = 4*it + w. Per-wave O partials
// are reduced across waves through LDS at the end (no store race).
__global__ __launch_bounds__(256) void s4d_fused(
    const float* __restrict__ KnT, const float* __restrict__ VT,
    const float* __restrict__ QT, const unsigned short* __restrict__ TABG,
    const unsigned short* __restrict__ cb2pack,
    const unsigned short* __restrict__ kdpack,
    const float* __restrict__ Dd, float* __restrict__ OT) {
  __shared__ __align__(16) unsigned short SHu[47168];
  const int tid = threadIdx.x;
  const int l = tid & 63, w = tid >> 6;
  const int l15 = l & 15, q = l >> 4;
  const int h = blockIdx.x >> 6, j = blockIdx.x & 63;
  const int dv = (h << 6) + j;

  // ---- shared table + V-row load ----
  {
    const float4_a* src = (const float4_a*)TABG;
    float4_a* dst = (float4_a*)SHu;
#pragma unroll
    for (int u = 0; u < 9; ++u) {
      const int idx = tid + 256 * u;
      if (idx < 2272) dst[idx] = src[idx];
    }
    float_a* Vr = (float_a*)(SHu + 18176);
    const float4 vx = *(const float4*)&VT[dv * S + 4 * tid];
    float4_a vw = {vx.x, vx.y, vx.z, vx.w};
    *(float4_a*)&Vr[4 * tid] = vw;
  }

  // ---- initial prefetch (channel i = w) ----
  float4 kx[4], qtv[4];
  float c2r, c2i, dd;
  unsigned int kdv;
  {
    const int i = w;
    const int dk = (h << 6) + i;
    const int c = (h << 12) + (i << 6) + j;
    const int kb = dk * S + 4 * l;
#pragma unroll
    for (int s = 0; s < 4; ++s) {
      kx[s] = *(const float4*)&KnT[kb + 256 * s];
      qtv[s] = *(const float4*)&QT[kb + 256 * s];
    }
    c2r = bf2f(cb2pack[c * 128 + l]);
    c2i = bf2f(cb2pack[c * 128 + 64 + l]);
    kdv = *(const uint_a*)&kdpack[c * 128 + 2 * l];
    dd = Dd[c];
  }
  __syncthreads();

  const unsigned short* PAre = SHu;
  const unsigned short* PAim = SHu + 4608;
  const unsigned short* PCc = SHu + 9216;
  const float_a* dA64v = (const float_a*)(SHu + 17920);
  const float_a* Vrow = (const float_a*)(SHu + 18176);
  unsigned short* WB = SHu + 20224 + w * 6736;
  unsigned short* Ub = WB;                    // [16][72] bf16
  unsigned short* Xcb = WB + 1152;            // [16][136] bf16
  unsigned short* Sc = WB + 3328;             // [16][136] bf16 (aliases yout)
  float_a* yout = (float_a*)(WB + 3328);      // [16][68] f32
  unsigned short* kdSH = WB + 5648;           // [8][136]
  uint_a* kdR32 = (uint_a*)(WB + 5504);       // [68] uints as [136] ushorts

  const float er = dA64v[2 * l], ei = dA64v[2 * l + 1];
  float4 Oa[4];
#pragma unroll
  for (int s = 0; s < 4; ++s) Oa[s] = make_float4(0.f, 0.f, 0.f, 0.f);

#pragma unroll 1
  for (int it = 0; it < 16; ++it) {
    // ---- prefetch next channel ----
    float4 nkx[4], nqt[4];
    float nc2r = 0.f, nc2i = 0.f, ndd = 0.f;
    unsigned int nkdv = 0;
    if (it < 15) {
      const int i = (it + 1) * 4 + w;
      const int dk = (h << 6) + i;
      const int c = (h << 12) + (i << 6) + j;
      const int kb = dk * S + 4 * l;
#pragma unroll
      for (int s = 0; s < 4; ++s) {
        nkx[s] = *(const float4*)&KnT[kb + 256 * s];
        nqt[s] = *(const float4*)&QT[kb + 256 * s];
      }
      nc2r = bf2f(cb2pack[c * 128 + l]);
      nc2i = bf2f(cb2pack[c * 128 + 64 + l]);
      nkdv = *(const uint_a*)&kdpack[c * 128 + 2 * l];
      ndd = Dd[c];
    }

    // ---- 1) u fill ----
#pragma unroll
    for (int s = 0; s < 4; ++s) {
      const int t = 4 * l + 256 * s;
      const int g = t >> 6, r = t & 63;
      const float vx0 = Vrow[t], vx1 = Vrow[t + 1], vx2 = Vrow[t + 2], vx3 = Vrow[t + 3];
      uint2_a pp;
      pp.x = (unsigned int)f2bf(kx[s].x * vx0) | ((unsigned int)f2bf(kx[s].y * vx1) << 16);
      pp.y = (unsigned int)f2bf(kx[s].z * vx2) | ((unsigned int)f2bf(kx[s].w * vx3) << 16);
      *(uint2_a*)&Ub[g * 72 + r] = pp;
    }
    // ---- 2) kdR + 8 shifted copies ----
    kdR32[l] = kdv;
    if (l < 4) kdR32[64 + l] = 0;
    asm volatile("" ::: "memory");
#pragma unroll
    for (int s = 0; s < 8; ++s) {
      unsigned int v;
      if ((s & 1) == 0) {
        v = kdR32[l + (s >> 1)];
      } else {
        const unsigned int d0 = kdR32[l + ((s - 1) >> 1)];
        const unsigned int d1 = kdR32[l + ((s + 1) >> 1)];
        v = (d0 >> 16) | (d1 << 16);
      }
      *(uint_a*)&kdSH[s * 136 + 2 * l] = v;
    }
    asm volatile("" ::: "memory");
    // ---- 3) phase A: s~[n][g] = sum_r Pow[63-r][n] * u[r][g] ----
    const shortx8 b0 = *(const shortx8_a*)&Ub[l15 * 72 + 8 * q];
    const shortx8 b1 = *(const shortx8_a*)&Ub[l15 * 72 + 8 * q + 32];
#pragma unroll
    for (int tt = 0; tt < 4; ++tt) {
      const int rowb = (tt * 16 + l15) * 72 + 8 * q;
      const shortx8 ar0 = *(const shortx8_a*)&PAre[rowb];
      const shortx8 ar1 = *(const shortx8_a*)&PAre[rowb + 32];
      const shortx8 ai0 = *(const shortx8_a*)&PAim[rowb];
      const shortx8 ai1 = *(const shortx8_a*)&PAim[rowb + 32];
      floatx4 z = {0.f, 0.f, 0.f, 0.f};
      floatx4 sre = __builtin_amdgcn_mfma_f32_16x16x32_bf16(ar0, b0, z, 0, 0, 0);
      sre = __builtin_amdgcn_mfma_f32_16x16x32_bf16(ar1, b1, sre, 0, 0, 0);
      floatx4 sim = __builtin_amdgcn_mfma_f32_16x16x32_bf16(ai0, b0, z, 0, 0, 0);
      sim = __builtin_amdgcn_mfma_f32_16x16x32_bf16(ai1, b1, sim, 0, 0, 0);
      const int sb = l15 * 136 + tt * 16 + 4 * q;
      *(uint_a*)&Sc[sb] = (unsigned int)f2bf(sre[0]) | ((unsigned int)f2bf(sre[1]) << 16);
      *(uint_a*)&Sc[sb + 2] = (unsigned int)f2bf(sre[2]) | ((unsigned int)f2bf(sre[3]) << 16);
      *(uint_a*)&Sc[sb + 64] = (unsigned int)f2bf(sim[0]) | ((unsigned int)f2bf(sim[1]) << 16);
      *(uint_a*)&Sc[sb + 66] = (unsigned int)f2bf(sim[2]) | ((unsigned int)f2bf(sim[3]) << 16);
    }
    asm volatile("" ::: "memory");
    // ---- 4) chunk scan (lane = state n); Xc = cb2 * x_pre ----
    {
      float xr = 0.f, xi = 0.f;
#pragma unroll
      for (int g = 0; g < 16; ++g) {
        Xcb[g * 136 + l] = f2bf(c2r * xr - c2i * xi);
        Xcb[g * 136 + 64 + l] = f2bf(c2r * xi + c2i * xr);
        const float sr = bf2f(Sc[g * 136 + l]);
        const float si = bf2f(Sc[g * 136 + 64 + l]);
        const float nr = er * xr - ei * xi + sr;
        xi = er * xi + ei * xr + si;
        xr = nr;
      }
    }
    asm volatile("" ::: "memory");
    // ---- 5) phase C: y[g][r] = Xc @ PCc^T + Ub @ T^T ----
    floatx4 acc[4];
#pragma unroll
    for (int tt = 0; tt < 4; ++tt) acc[tt] = (floatx4){0.f, 0.f, 0.f, 0.f};
#pragma unroll
    for (int k = 0; k < 4; ++k) {
      const shortx8 xa = *(const shortx8_a*)&Xcb[l15 * 136 + 8 * q + 32 * k];
#pragma unroll
      for (int tt = 0; tt < 4; ++tt) {
        const shortx8 pb = *(const shortx8_a*)&PCc[(tt * 16 + l15) * 136 + 8 * q + 32 * k];
        acc[tt] = __builtin_amdgcn_mfma_f32_16x16x32_bf16(xa, pb, acc[tt], 0, 0, 0);
      }
    }
#pragma unroll
    for (int k = 0; k < 2; ++k) {
      const shortx8 ua = (k == 0) ? b0 : b1;
#pragma unroll
      for (int tt = 0; tt < 4; ++tt) {
        const int r = tt * 16 + l15;
        const int sSh = (8 - (r & 7)) & 7;
        const int addr = sSh * 136 + (64 - r - sSh) + 8 * q + 32 * k;
        const shortx8 kb = *(const shortx8_a*)&kdSH[addr];
        acc[tt] = __builtin_amdgcn_mfma_f32_16x16x32_bf16(ua, kb, acc[tt], 0, 0, 0);
      }
    }
    // ---- 6) epilogue -> yout ----
#pragma unroll
    for (int tt = 0; tt < 4; ++tt) {
      const int r = tt * 16 + l15;
#pragma unroll
      for (int v = 0; v < 4; ++v) {
        const int g = 4 * q + v;
        yout[g * 68 + r] = acc[tt][v] + dd * bf2f(Ub[g * 72 + r]);
      }
    }
    asm volatile("" ::: "memory");
    // ---- 7) contraction: O[t] += QT[dk][t] * y[t] ----
#pragma unroll
    for (int s = 0; s < 4; ++s) {
      const int t = 4 * l + 256 * s;
      const float4_a y4 = *(const float4_a*)&yout[(t >> 6) * 68 + (t & 63)];
      Oa[s].x += qtv[s].x * y4.x;
      Oa[s].y += qtv[s].y * y4.y;
      Oa[s].z += qtv[s].z * y4.z;
      Oa[s].w += qtv[s].w * y4.w;
    }
    asm volatile("" ::: "memory");
    // ---- rotate prefetch ----
#pragma unroll
    for (int s = 0; s < 4; ++s) { kx[s] = nkx[s]; qtv[s] = nqt[s]; }
    c2r = nc2r; c2i = nc2i; kdv = nkdv; dd = ndd;
  }

  // ---- cross-wave reduction of O partials (fixes the OT store race) ----
  {
    float_a* Ow = (float_a*)WB;
#pragma unroll
    for (int s = 0; s < 4; ++s) {
      float4_a vv = {Oa[s].x, Oa[s].y, Oa[s].z, Oa[s].w};
      *(float4_a*)&Ow[4 * l + 256 * s] = vv;
    }
  }
  __syncthreads();
  {
    const int tq = 256 * w + 4 * l;   // this wave owns t-quarter w
    float4_a acc = {0.f, 0.f, 0.f, 0.f};
#pragma unroll
    for (int w2 = 0; w2 < 4; ++w2) {
      const float_a* Ow2 = (const float_a*)(SHu + 20224 + w2 * 6736);
      acc += *(const float4_a*)&Ow2[tq];
    }
    *(float4_a*)&OT[dv * S + tq] = acc;
  }
}

extern "C" void kernel_launch(void* const* d_in, const int* in_sizes, int n_in,
                              void* d_out, int out_size, void* d_ws, size_t ws_size,
                              hipStream_t stream) {
  const float* x   = (const float*)d_in[0];
  const float* WQ  = (const float*)d_in[1];
  const float* WK  = (const float*)d_in[2];
  const float* WV  = (const float*)d_in[3];
  const float* WO  = (const float*)d_in[4];
  const float* Cs  = (const float*)d_in[5];
  const float* Ds  = (const float*)d_in[6];
  const float* Are = (const float*)d_in[7];
  const float* Aim = (const float*)d_in[8];
  const float* Cre = (const float*)d_in[9];
  const float* Cim = (const float*)d_in[10];
  const float* Dd  = (const float*)d_in[11];
  float* out = (float*)d_out;

  char* ws = (char*)d_ws;
  const size_t SD = (size_t)S * D * 4;
  float* Q    = (float*)(ws + 0 * SD);
  float* Kraw = (float*)(ws + 1 * SD);
  float* V    = (float*)(ws + 2 * SD);
  float* Kn   = (float*)(ws + 3 * SD);
  float* KnT  = (float*)(ws + 4 * SD);
  float* VT   = (float*)(ws + 5 * SD);
  float* QT   = (float*)(ws + 6 * SD);
  float* OT   = (float*)(ws + 7 * SD);
  float* O1   = (float*)(ws + 8 * SD);
  float* CsT  = (float*)(ws + 9 * SD);
  unsigned short* TABG    = (unsigned short*)(ws + 9 * SD + 131072);
  unsigned short* PCc2g   = (unsigned short*)(ws + 9 * SD + 167936);
  unsigned short* cb2pack = (unsigned short*)(ws + 9 * SD + 185344);
  unsigned short* kdpack  = (unsigned short*)(ws + 9 * SD + 185344 + 8388608);

  dim3 ggrid(D / 64, S / 64);
  gemm_abT<<<ggrid, 256, 0, stream>>>(x, WQ, Q, S, D, D);
  gemm_abT<<<ggrid, 256, 0, stream>>>(x, WK, Kraw, S, D, D);
  gemm_abT<<<ggrid, 256, 0, stream>>>(x, WV, V, S, D, D);
  dim3 cst_grid(HID / 32, D / 32);
  transpose_fp32<<<cst_grid, 256, 0, stream>>>(Cs, CsT, D, HID);
  shift_ssm<<<S, D, 0, stream>>>(Kraw, CsT, Ds, Kn);
  dim3 tgrid(D / 32, S / 32);
  transpose_fp32<<<tgrid, 256, 0, stream>>>(Kn, KnT, S, D);
  transpose_fp32<<<tgrid, 256, 0, stream>>>(V, VT, S, D);
  transpose_fp32<<<tgrid, 256, 0, stream>>>(Q, QT, S, D);
  prep_tables<<<1, 64, 0, stream>>>(Are, Aim, TABG, PCc2g);
  prep_cb<<<CD * 64 / 256, 256, 0, stream>>>(Are, Aim, Cre, Cim, cb2pack);
  prep_kd<<<CD / 16, 256, 0, stream>>>(cb2pack, PCc2g, kdpack);
  s4d_fused<<<512, 256, 0, stream>>>(KnT, VT, QT, TABG, cb2pack, kdpack, Dd, OT);
  dim3 ogrid(S / 32, D / 32);
  transpose_fp32<<<ogrid, 256, 0, stream>>>(OT, O1, D, S);
  gemm_abT<<<ggrid, 256, 0, stream>>>(O1, WO, out, S, D, D);
}

// Round 7
// 267.171 us; speedup vs baseline: 9.6866x; 1.4619x over previous
//
#include <hip/hip_runtime.h>

#define S 1024
#define D 512
#define HID 64
#define CD 32768
#define DT 0.1f

typedef __attribute__((ext_vector_type(4))) float floatx4;
typedef __attribute__((ext_vector_type(8))) short shortx8;
// may_alias variants for type-punned LDS/global access (TBAA-safe)
typedef short shortx8_a __attribute__((ext_vector_type(8), may_alias));
typedef short shortx4_a __attribute__((ext_vector_type(4), may_alias));
typedef unsigned int uint_a __attribute__((may_alias));
typedef unsigned int uint2_a __attribute__((ext_vector_type(2), may_alias));
typedef float float4_a __attribute__((ext_vector_type(4), may_alias));
typedef float float_a __attribute__((may_alias));

__device__ __forceinline__ unsigned short f2bf(float f) {
  union { float f; unsigned int u; } v;
  v.f = f;
  unsigned int r = v.u + 0x7FFFu + ((v.u >> 16) & 1u);
  return (unsigned short)(r >> 16);
}
__device__ __forceinline__ float bf2f(unsigned short h) {
  union { unsigned int u; float f; } v;
  v.u = ((unsigned int)h) << 16;
  return v.f;
}

// ------ gemm_qkvT: {Q,Kraw,V}T[n][m] = sum_k x[m][k]*W[n][k], transposed out -
__global__ __launch_bounds__(256) void gemm_qkvT(
    const float* __restrict__ x, const float* __restrict__ WQ,
    const float* __restrict__ WK, const float* __restrict__ WV,
    float* __restrict__ QT, float* __restrict__ KrawT, float* __restrict__ VT) {
  __shared__ float As[64][17];
  __shared__ float Bs[64][17];
  __shared__ float Ct[64][68];
  const int tx = threadIdx.x & 15, ty = threadIdx.x >> 4;
  const int mat = blockIdx.x >> 3;
  const int n0 = (blockIdx.x & 7) * 64;
  const int m0 = blockIdx.y * 64;
  const float* Wsel = (mat == 0) ? WQ : (mat == 1) ? WK : WV;
  float* CT = (mat == 0) ? QT : (mat == 1) ? KrawT : VT;
  float acc[4][4] = {};
  for (int k0 = 0; k0 < D; k0 += 16) {
#pragma unroll
    for (int r = 0; r < 4; ++r) {
      const int row = ty + r * 16;
      As[row][tx] = x[(m0 + row) * D + k0 + tx];
      Bs[row][tx] = Wsel[(n0 + row) * D + k0 + tx];
    }
    __syncthreads();
#pragma unroll
    for (int kk = 0; kk < 16; ++kk) {
      float a[4], b[4];
#pragma unroll
      for (int i = 0; i < 4; ++i) a[i] = As[ty * 4 + i][kk];
#pragma unroll
      for (int j = 0; j < 4; ++j) b[j] = Bs[tx * 4 + j][kk];
#pragma unroll
      for (int i = 0; i < 4; ++i)
#pragma unroll
        for (int j = 0; j < 4; ++j) acc[i][j] += a[i] * b[j];
    }
    __syncthreads();
  }
  // transposed epilogue through LDS -> coalesced CT[n][m] stores
#pragma unroll
  for (int i = 0; i < 4; ++i)
#pragma unroll
    for (int j = 0; j < 4; ++j) Ct[tx * 4 + j][ty * 4 + i] = acc[i][j];
  __syncthreads();
  const int col4 = (threadIdx.x & 15) * 4;
  const int rbase = (threadIdx.x >> 4) * 4;
#pragma unroll
  for (int rr = 0; rr < 4; ++rr) {
    const int row = rbase + rr;
    *(float4_a*)&CT[(n0 + row) * S + m0 + col4] = *(const float4_a*)&Ct[row][col4];
  }
}

// ------ shift_ssmT: KnT[d][t] = Ds[d]*KrawT[d][t] + sum_j Cs[d][j]*KrawT[d][t-j]
__global__ __launch_bounds__(256) void shift_ssmT(const float* __restrict__ KrawT,
                                                  const float* __restrict__ Cs,
                                                  const float* __restrict__ Ds,
                                                  float* __restrict__ KnT) {
  __shared__ float kpad[64 + S];
  __shared__ float taps[64];
  const int d = blockIdx.x, tid = threadIdx.x;
  if (tid < 64) {
    kpad[tid] = 0.0f;
    taps[tid] = Cs[d * HID + tid];
  }
  *(float4_a*)&kpad[64 + 4 * tid] = *(const float4_a*)&KrawT[d * S + 4 * tid];
  const float dskip = Ds[d];
  __syncthreads();
#pragma unroll
  for (int s = 0; s < 4; ++s) {
    const int t = tid + 256 * s;
    float acc = dskip * kpad[64 + t];
    for (int j = 0; j < 64; ++j) acc += taps[j] * kpad[64 + t - j];
    KnT[d * S + t] = acc;
  }
}

// ---------------- prep_tables: shared dA-power tables (1 block) -------------
__global__ void prep_tables(const float* __restrict__ Are, const float* __restrict__ Aim,
                            unsigned short* __restrict__ TABG,
                            unsigned short* __restrict__ PCc2g) {
  const int n = threadIdx.x;  // 64 threads
  unsigned short* PAre = TABG;
  unsigned short* PAim = TABG + 4608;
  unsigned short* PCc  = TABG + 9216;
  float_a* dA64 = (float_a*)(TABG + 17920);
  const float ar = Are[n], ai = Aim[n];
  const float den_re = 1.0f - 0.05f * ar;
  const float den_im = -0.05f * ai;
  const float num_re = 1.0f + 0.05f * ar;
  const float num_im = 0.05f * ai;
  const float inv_d2 = 1.0f / (den_re * den_re + den_im * den_im);
  const float dAr = (num_re * den_re + num_im * den_im) * inv_d2;
  const float dAi = (num_im * den_re - num_re * den_im) * inv_d2;
  PAre[n * 72 + 63] = f2bf(1.0f);
  PAim[n * 72 + 63] = 0;
  PCc2g[n] = f2bf(1.0f);
  PCc2g[64 + n] = 0;
  float pr = 1.0f, pi = 0.0f;
  for (int k = 1; k <= 64; ++k) {
    const float nr = pr * dAr - pi * dAi;
    pi = pr * dAi + pi * dAr;
    pr = nr;
    if (k <= 63) {
      PAre[n * 72 + 63 - k] = f2bf(pr);
      PAim[n * 72 + 63 - k] = f2bf(pi);
      PCc2g[k * 136 + n] = f2bf(pr);
      PCc2g[k * 136 + 64 + n] = f2bf(-pi);
    }
    PCc[(k - 1) * 136 + n] = f2bf(pr);
    PCc[(k - 1) * 136 + 64 + n] = f2bf(-pi);
    if (k == 64) { dA64[2 * n] = pr; dA64[2 * n + 1] = pi; }
  }
}

// ------ prep_cbkd: cb2pack[c][128] bf16 + kd GEMM -> kdpack[c][128] (kdR) ---
__global__ __launch_bounds__(256) void prep_cbkd(
    const float* __restrict__ Are, const float* __restrict__ Aim,
    const float* __restrict__ Cre, const float* __restrict__ Cim,
    const unsigned short* __restrict__ PCc2g,
    unsigned short* __restrict__ cb2pack, unsigned short* __restrict__ kdpack) {
  __shared__ __align__(16) unsigned short cbs[16][136];
  __shared__ float an[128];
  const int tid = threadIdx.x;
  const int c0 = blockIdx.x << 4;
  if (tid < 64) an[tid] = Are[tid];
  else if (tid < 128) an[tid - 64 + 64] = Aim[tid - 64];
  __syncthreads();
#pragma unroll
  for (int ii = 0; ii < 4; ++ii) {
    const int idx = tid + 256 * ii;
    const int ci = idx >> 6, n = idx & 63;
    const int c = c0 + ci;
    const float ar = an[n], ai = an[64 + n];
    const float den_re = 1.0f - 0.05f * ar;
    const float den_im = -0.05f * ai;
    const float inv_d2 = 1.0f / (den_re * den_re + den_im * den_im);
    const float dBr = DT * den_re * inv_d2;
    const float dBi = -DT * den_im * inv_d2;
    const float cr = Cre[c * HID + n], cim = Cim[c * HID + n];
    const unsigned short re = f2bf(2.0f * (cr * dBr - cim * dBi));
    const unsigned short im = f2bf(2.0f * (cr * dBi + cim * dBr));
    cbs[ci][n] = re;
    cbs[ci][64 + n] = im;
    cb2pack[c * 128 + n] = re;
    cb2pack[c * 128 + 64 + n] = im;
  }
  __syncthreads();
  const int l = tid & 63, w = tid >> 6;
  const int l15 = l & 15, q = l >> 4;
  floatx4 acc = {0.f, 0.f, 0.f, 0.f};
#pragma unroll
  for (int k = 0; k < 4; ++k) {
    const shortx8 a = *(const shortx8_a*)&cbs[l15][8 * q + 32 * k];
    const shortx8 b = *(const shortx8_a*)&PCc2g[(16 * w + l15) * 136 + 8 * q + 32 * k];
    acc = __builtin_amdgcn_mfma_f32_16x16x32_bf16(a, b, acc, 0, 0, 0);
  }
  const int dlt = 16 * w + l15;
#pragma unroll
  for (int v = 0; v < 4; ++v)
    kdpack[(c0 + 4 * q + v) * 128 + 64 - dlt] = f2bf(acc[v]);
  const int row = tid >> 4, p = tid & 15;
#pragma unroll
  for (int k2 = 0; k2 < 4; ++k2) {
    const int idx = p + 16 * k2;
    const int m = (idx == 0) ? 0 : 64 + idx;
    kdpack[(c0 + row) * 128 + m] = 0;
  }
}

// ---------------- s4d_fused: diagonal SSM + Q-contraction -------------------
// Block = (h, j): wave w handles channels i = 4*it + w. LDS 68.7 KB -> 2
// blocks/CU. Per-wave buffer SXY serves Sc -> Xcb -> yout sequentially.
__global__ __launch_bounds__(256) void s4d_fused(
    const float* __restrict__ KnT, const float* __restrict__ VT,
    const float* __restrict__ QT, const unsigned short* __restrict__ TABG,
    const unsigned short* __restrict__ cb2pack,
    const unsigned short* __restrict__ kdpack,
    const float* __restrict__ Dd, float* __restrict__ OT) {
  __shared__ __align__(16) unsigned short SHu[34368];  // 68736 B
  const int tid = threadIdx.x;
  const int l = tid & 63, w = tid >> 6;
  const int l15 = l & 15, q = l >> 4;
  const int h = blockIdx.x >> 6, j = blockIdx.x & 63;
  const int dv = (h << 6) + j;

  // ---- shared tables (36352 B = 2272 float4) ----
  {
    const float4_a* src = (const float4_a*)TABG;
    float4_a* dst = (float4_a*)SHu;
#pragma unroll
    for (int u = 0; u < 9; ++u) {
      const int idx = tid + 256 * u;
      if (idx < 2272) dst[idx] = src[idx];
    }
  }
  // ---- V row slice in registers (each thread only needs its own t-slice) ----
  float4 vvr[4];
#pragma unroll
  for (int s = 0; s < 4; ++s)
    vvr[s] = *(const float4*)&VT[dv * S + 4 * l + 256 * s];

  // ---- initial prefetch (channel i = w) ----
  float4 kx[4], qtv[4];
  float c2r, c2i, dd;
  unsigned int kdv;
  {
    const int i = w;
    const int dk = (h << 6) + i;
    const int c = (h << 12) + (i << 6) + j;
    const int kb = dk * S + 4 * l;
#pragma unroll
    for (int s = 0; s < 4; ++s) {
      kx[s] = *(const float4*)&KnT[kb + 256 * s];
      qtv[s] = *(const float4*)&QT[kb + 256 * s];
    }
    c2r = bf2f(cb2pack[c * 128 + l]);
    c2i = bf2f(cb2pack[c * 128 + 64 + l]);
    kdv = *(const uint_a*)&kdpack[c * 128 + 2 * l];
    dd = Dd[c];
  }
  __syncthreads();

  const unsigned short* PAre = SHu;
  const unsigned short* PAim = SHu + 4608;
  const unsigned short* PCc = SHu + 9216;
  const float_a* dA64v = (const float_a*)(SHu + 17920);
  unsigned short* WB = SHu + 18176 + w * 4048;
  unsigned short* Ub = WB;                    // [16][72] bf16
  unsigned short* SXY = WB + 1152;            // [16][136]: Sc -> Xcb -> yout
  uint_a* kdR32 = (uint_a*)(WB + 3328);       // 68 uints (+pad)
  unsigned short* kdSH = WB + 3472;           // [4][136]
  float_a* yf = (float_a*)SXY;                // [16][68] f32 view

  const float er = dA64v[2 * l], ei = dA64v[2 * l + 1];
  float4 Oa[4];
#pragma unroll
  for (int s = 0; s < 4; ++s) Oa[s] = make_float4(0.f, 0.f, 0.f, 0.f);

#pragma unroll 1
  for (int it = 0; it < 16; ++it) {
    // ---- prefetch next channel ----
    float4 nkx[4], nqt[4];
    float nc2r = 0.f, nc2i = 0.f, ndd = 0.f;
    unsigned int nkdv = 0;
    if (it < 15) {
      const int i = (it + 1) * 4 + w;
      const int dk = (h << 6) + i;
      const int c = (h << 12) + (i << 6) + j;
      const int kb = dk * S + 4 * l;
#pragma unroll
      for (int s = 0; s < 4; ++s) {
        nkx[s] = *(const float4*)&KnT[kb + 256 * s];
        nqt[s] = *(const float4*)&QT[kb + 256 * s];
      }
      nc2r = bf2f(cb2pack[c * 128 + l]);
      nc2i = bf2f(cb2pack[c * 128 + 64 + l]);
      nkdv = *(const uint_a*)&kdpack[c * 128 + 2 * l];
      ndd = Dd[c];
    }

    // ---- 1) u fill ----
#pragma unroll
    for (int s = 0; s < 4; ++s) {
      const int t = 4 * l + 256 * s;
      const int g = t >> 6, r = t & 63;
      uint2_a pp;
      pp.x = (unsigned int)f2bf(kx[s].x * vvr[s].x) | ((unsigned int)f2bf(kx[s].y * vvr[s].y) << 16);
      pp.y = (unsigned int)f2bf(kx[s].z * vvr[s].z) | ((unsigned int)f2bf(kx[s].w * vvr[s].w) << 16);
      *(uint2_a*)&Ub[g * 72 + r] = pp;
    }
    // ---- 2) kdR + 4 shifted copies (mod-4 residues) ----
    kdR32[l] = kdv;
    if (l < 4) kdR32[64 + l] = 0;
    asm volatile("" ::: "memory");
#pragma unroll
    for (int s2 = 0; s2 < 4; ++s2) {
      unsigned int v;
      if (s2 == 0) {
        v = kdR32[l];
      } else if (s2 == 1) {
        v = (kdR32[l] >> 16) | (kdR32[l + 1] << 16);
      } else if (s2 == 2) {
        v = kdR32[l + 1];
      } else {
        v = (kdR32[l + 1] >> 16) | (kdR32[l + 2] << 16);
      }
      *(uint_a*)&kdSH[s2 * 136 + 2 * l] = v;
    }
    asm volatile("" ::: "memory");
    // ---- 3) phase A: s~[g][n] via MFMA ----
    const shortx8 b0 = *(const shortx8_a*)&Ub[l15 * 72 + 8 * q];
    const shortx8 b1 = *(const shortx8_a*)&Ub[l15 * 72 + 8 * q + 32];
#pragma unroll
    for (int tt = 0; tt < 4; ++tt) {
      const int rowb = (tt * 16 + l15) * 72 + 8 * q;
      const shortx8 ar0 = *(const shortx8_a*)&PAre[rowb];
      const shortx8 ar1 = *(const shortx8_a*)&PAre[rowb + 32];
      const shortx8 ai0 = *(const shortx8_a*)&PAim[rowb];
      const shortx8 ai1 = *(const shortx8_a*)&PAim[rowb + 32];
      floatx4 z = {0.f, 0.f, 0.f, 0.f};
      floatx4 sre = __builtin_amdgcn_mfma_f32_16x16x32_bf16(ar0, b0, z, 0, 0, 0);
      sre = __builtin_amdgcn_mfma_f32_16x16x32_bf16(ar1, b1, sre, 0, 0, 0);
      floatx4 sim = __builtin_amdgcn_mfma_f32_16x16x32_bf16(ai0, b0, z, 0, 0, 0);
      sim = __builtin_amdgcn_mfma_f32_16x16x32_bf16(ai1, b1, sim, 0, 0, 0);
      const int sb = l15 * 136 + tt * 16 + 4 * q;
      *(uint_a*)&SXY[sb] = (unsigned int)f2bf(sre[0]) | ((unsigned int)f2bf(sre[1]) << 16);
      *(uint_a*)&SXY[sb + 2] = (unsigned int)f2bf(sre[2]) | ((unsigned int)f2bf(sre[3]) << 16);
      *(uint_a*)&SXY[sb + 64] = (unsigned int)f2bf(sim[0]) | ((unsigned int)f2bf(sim[1]) << 16);
      *(uint_a*)&SXY[sb + 66] = (unsigned int)f2bf(sim[2]) | ((unsigned int)f2bf(sim[3]) << 16);
    }
    asm volatile("" ::: "memory");
    // ---- 4) chunk scan: read Sc[g] THEN overwrite with Xcb[g] (same lane) ----
    {
      float xr = 0.f, xi = 0.f;
#pragma unroll
      for (int g = 0; g < 16; ++g) {
        const float sr = bf2f(SXY[g * 136 + l]);
        const float si = bf2f(SXY[g * 136 + 64 + l]);
        SXY[g * 136 + l] = f2bf(c2r * xr - c2i * xi);
        SXY[g * 136 + 64 + l] = f2bf(c2r * xi + c2i * xr);
        const float nr = er * xr - ei * xi + sr;
        xi = er * xi + ei * xr + si;
        xr = nr;
      }
    }
    asm volatile("" ::: "memory");
    // ---- 5) phase C MFMAs: inter (Xcb @ PCc^T) + local (Ub @ Toeplitz^T) ----
    floatx4 acc[4];
#pragma unroll
    for (int tt = 0; tt < 4; ++tt) acc[tt] = (floatx4){0.f, 0.f, 0.f, 0.f};
#pragma unroll
    for (int k = 0; k < 4; ++k) {
      const shortx8 xa = *(const shortx8_a*)&SXY[l15 * 136 + 8 * q + 32 * k];
#pragma unroll
      for (int tt = 0; tt < 4; ++tt) {
        const shortx8 pb = *(const shortx8_a*)&PCc[(tt * 16 + l15) * 136 + 8 * q + 32 * k];
        acc[tt] = __builtin_amdgcn_mfma_f32_16x16x32_bf16(xa, pb, acc[tt], 0, 0, 0);
      }
    }
#pragma unroll
    for (int k = 0; k < 2; ++k) {
      const shortx8 ua = (k == 0) ? b0 : b1;
#pragma unroll
      for (int tt = 0; tt < 4; ++tt) {
        const int r = tt * 16 + l15;
        const int sSh = (4 - (r & 3)) & 3;
        const int addr = sSh * 136 + (64 - r - sSh) + 8 * q + 32 * k;
        const shortx4_a lo = *(const shortx4_a*)&kdSH[addr];
        const shortx4_a hi = *(const shortx4_a*)&kdSH[addr + 4];
        const shortx8 kb8 = __builtin_shufflevector(lo, hi, 0, 1, 2, 3, 4, 5, 6, 7);
        acc[tt] = __builtin_amdgcn_mfma_f32_16x16x32_bf16(ua, kb8, acc[tt], 0, 0, 0);
      }
    }
    // ---- 6) epilogue -> yf (f32 view of SXY; Xcb fully consumed above) ----
#pragma unroll
    for (int tt = 0; tt < 4; ++tt) {
      const int r = tt * 16 + l15;
#pragma unroll
      for (int v = 0; v < 4; ++v) {
        const int g = 4 * q + v;
        yf[g * 68 + r] = acc[tt][v] + dd * bf2f(Ub[g * 72 + r]);
      }
    }
    asm volatile("" ::: "memory");
    // ---- 7) contraction: O[t] += QT[dk][t] * y[t] ----
#pragma unroll
    for (int s = 0; s < 4; ++s) {
      const int t = 4 * l + 256 * s;
      const float4_a y4 = *(const float4_a*)&yf[(t >> 6) * 68 + (t & 63)];
      Oa[s].x += qtv[s].x * y4.x;
      Oa[s].y += qtv[s].y * y4.y;
      Oa[s].z += qtv[s].z * y4.z;
      Oa[s].w += qtv[s].w * y4.w;
    }
    asm volatile("" ::: "memory");
    // ---- rotate prefetch ----
#pragma unroll
    for (int s = 0; s < 4; ++s) { kx[s] = nkx[s]; qtv[s] = nqt[s]; }
    c2r = nc2r; c2i = nc2i; kdv = nkdv; dd = ndd;
  }

  // ---- cross-wave reduction of O partials ----
  {
    float_a* Ow = (float_a*)WB;
#pragma unroll
    for (int s = 0; s < 4; ++s) {
      float4_a vv = {Oa[s].x, Oa[s].y, Oa[s].z, Oa[s].w};
      *(float4_a*)&Ow[4 * l + 256 * s] = vv;
    }
  }
  __syncthreads();
  {
    const int tq = 256 * w + 4 * l;
    float4_a acc = {0.f, 0.f, 0.f, 0.f};
#pragma unroll
    for (int w2 = 0; w2 < 4; ++w2) {
      const float_a* Ow2 = (const float_a*)(SHu + 18176 + w2 * 4048);
      acc += *(const float4_a*)&Ow2[tq];
    }
    *(float4_a*)&OT[dv * S + tq] = acc;
  }
}

// ------ gemm_outT: out[m][n] = sum_k OT[k][m] * WO[n][k] --------------------
__global__ __launch_bounds__(256) void gemm_outT(const float* __restrict__ OT,
                                                 const float* __restrict__ WO,
                                                 float* __restrict__ out) {
  __shared__ float As[16][68];
  __shared__ float Bs[64][17];
  const int tx = threadIdx.x & 15, ty = threadIdx.x >> 4;
  const int n0 = blockIdx.x * 64, m0 = blockIdx.y * 64;
  float acc[4][4] = {};
  for (int k0 = 0; k0 < D; k0 += 16) {
    {
      const int kk = threadIdx.x >> 4;
      const int mm = (threadIdx.x & 15) * 4;
      *(float4_a*)&As[kk][mm] = *(const float4_a*)&OT[(k0 + kk) * S + m0 + mm];
    }
#pragma unroll
    for (int r = 0; r < 4; ++r) {
      const int row = ty + r * 16;
      Bs[row][tx] = WO[(n0 + row) * D + k0 + tx];
    }
    __syncthreads();
#pragma unroll
    for (int kk = 0; kk < 16; ++kk) {
      const float4_a a4 = *(const float4_a*)&As[kk][ty * 4];
      float b[4];
#pragma unroll
      for (int jj = 0; jj < 4; ++jj) b[jj] = Bs[tx * 4 + jj][kk];
#pragma unroll
      for (int i = 0; i < 4; ++i)
#pragma unroll
        for (int jj = 0; jj < 4; ++jj) acc[i][jj] += a4[i] * b[jj];
    }
    __syncthreads();
  }
#pragma unroll
  for (int i = 0; i < 4; ++i)
#pragma unroll
    for (int jj = 0; jj < 4; ++jj)
      out[(m0 + ty * 4 + i) * D + n0 + tx * 4 + jj] = acc[i][jj];
}

extern "C" void kernel_launch(void* const* d_in, const int* in_sizes, int n_in,
                              void* d_out, int out_size, void* d_ws, size_t ws_size,
                              hipStream_t stream) {
  const float* x   = (const float*)d_in[0];
  const float* WQ  = (const float*)d_in[1];
  const float* WK  = (const float*)d_in[2];
  const float* WV  = (const float*)d_in[3];
  const float* WO  = (const float*)d_in[4];
  const float* Cs  = (const float*)d_in[5];
  const float* Ds  = (const float*)d_in[6];
  const float* Are = (const float*)d_in[7];
  const float* Aim = (const float*)d_in[8];
  const float* Cre = (const float*)d_in[9];
  const float* Cim = (const float*)d_in[10];
  const float* Dd  = (const float*)d_in[11];
  float* out = (float*)d_out;

  char* ws = (char*)d_ws;
  const size_t SD = (size_t)S * D * 4;   // 2 MB
  float* QT    = (float*)(ws + 0 * SD);
  float* KrawT = (float*)(ws + 1 * SD);
  float* VT    = (float*)(ws + 2 * SD);
  float* KnT   = (float*)(ws + 3 * SD);
  float* OT    = (float*)(ws + 4 * SD);
  unsigned short* TABG    = (unsigned short*)(ws + 5 * SD);                    // 36864 B
  unsigned short* PCc2g   = (unsigned short*)(ws + 5 * SD + 36864);            // 17408 B
  unsigned short* cb2pack = (unsigned short*)(ws + 5 * SD + 36864 + 17408);    // 8 MB
  unsigned short* kdpack  = (unsigned short*)(ws + 5 * SD + 36864 + 17408 + 8388608);  // 8 MB

  gemm_qkvT<<<dim3(24, 16), 256, 0, stream>>>(x, WQ, WK, WV, QT, KrawT, VT);
  shift_ssmT<<<512, 256, 0, stream>>>(KrawT, Cs, Ds, KnT);
  prep_tables<<<1, 64, 0, stream>>>(Are, Aim, TABG, PCc2g);
  prep_cbkd<<<CD / 16, 256, 0, stream>>>(Are, Aim, Cre, Cim, PCc2g, cb2pack, kdpack);
  s4d_fused<<<512, 256, 0, stream>>>(KnT, VT, QT, TABG, cb2pack, kdpack, Dd, OT);
  gemm_outT<<<dim3(8, 16), 256, 0, stream>>>(OT, WO, out);
}

// Round 8
// 203.809 us; speedup vs baseline: 12.6980x; 1.3109x over previous
//
#include <hip/hip_runtime.h>

#define S 1024
#define D 512
#define HID 64
#define CD 32768
#define DT 0.1f

typedef __attribute__((ext_vector_type(4))) float floatx4;
typedef __attribute__((ext_vector_type(8))) short shortx8;
// may_alias variants for type-punned LDS/global access (TBAA-safe)
typedef short shortx8_a __attribute__((ext_vector_type(8), may_alias));
typedef short shortx4_a __attribute__((ext_vector_type(4), may_alias));
typedef unsigned int uint_a __attribute__((may_alias));
typedef unsigned int uint2_a __attribute__((ext_vector_type(2), may_alias));
typedef float float4_a __attribute__((ext_vector_type(4), may_alias));
typedef float float_a __attribute__((may_alias));

__device__ __forceinline__ unsigned short f2bf(float f) {
  union { float f; unsigned int u; } v;
  v.f = f;
  unsigned int r = v.u + 0x7FFFu + ((v.u >> 16) & 1u);
  return (unsigned short)(r >> 16);
}
__device__ __forceinline__ float bf2f(unsigned short h) {
  union { unsigned int u; float f; } v;
  v.u = ((unsigned int)h) << 16;
  return v.f;
}
// hi/lo split: v ~= bf2f(h) + bf2f(lo), ~16-bit mantissa accuracy
__device__ __forceinline__ void cvt_hilo(float v, unsigned short& h, unsigned short& lo) {
  h = f2bf(v);
  lo = f2bf(v - bf2f(h));
}

// =====================  L1: fused QKV-GEMM + cbkd  ==========================
// blocks [0,384): {Q,Kraw,V}T[n][m] = sum_k x[m][k]*W[n][k] via bf16 hi/lo MFMA
// blocks [384,2432): per-16-channel cb2 + kd build (inline dA-power table)
__global__ __launch_bounds__(256) void fused_qkv_cbkd(
    const float* __restrict__ x, const float* __restrict__ WQ,
    const float* __restrict__ WK, const float* __restrict__ WV,
    const float* __restrict__ Are, const float* __restrict__ Aim,
    const float* __restrict__ Cre, const float* __restrict__ Cim,
    float* __restrict__ QT, float* __restrict__ KrawT, float* __restrict__ VT,
    unsigned short* __restrict__ cb2pack, unsigned short* __restrict__ kdpack) {
  __shared__ __align__(16) char LB[21760];
  const int tid = threadIdx.x;
  const int bid = blockIdx.x;
  const int l = tid & 63, w = tid >> 6;
  const int l15 = l & 15, q = l >> 4;

  if (bid < 384) {
    // ---------------- QKV GEMM: 64x64 tile, K=512, BK=32 ----------------
    unsigned short* Wh = (unsigned short*)LB;     // [64][40]
    unsigned short* Wl = Wh + 2560;
    unsigned short* Xh = Wl + 2560;
    unsigned short* Xl = Xh + 2560;
    float_a* Ct = (float_a*)LB;                   // [64][68], aliased after loop
    const int mat = bid >> 7;                     // /128
    const int rem = bid & 127;
    const int n0 = (rem & 7) * 64, m0 = (rem >> 3) * 64;
    const float* Wsel = (mat == 0) ? WQ : (mat == 1) ? WK : WV;
    float* CT = (mat == 0) ? QT : (mat == 1) ? KrawT : VT;

    floatx4 acc[4];
#pragma unroll
    for (int nt = 0; nt < 4; ++nt) acc[nt] = (floatx4){0.f, 0.f, 0.f, 0.f};

    for (int k0 = 0; k0 < D; k0 += 32) {
      if (k0) __syncthreads();
#pragma unroll
      for (int p = 0; p < 2; ++p) {
        const int idx = tid + 256 * p;
        const int row = idx >> 3, c4 = (idx & 7) * 4;
        const float4 wv = *(const float4*)&Wsel[(n0 + row) * D + k0 + c4];
        const float4 xv = *(const float4*)&x[(m0 + row) * D + k0 + c4];
        unsigned short h0, h1, h2, h3, g0, g1, g2, g3;
        cvt_hilo(wv.x, h0, g0); cvt_hilo(wv.y, h1, g1);
        cvt_hilo(wv.z, h2, g2); cvt_hilo(wv.w, h3, g3);
        uint2_a hv = {(unsigned int)h0 | ((unsigned int)h1 << 16),
                      (unsigned int)h2 | ((unsigned int)h3 << 16)};
        uint2_a lv = {(unsigned int)g0 | ((unsigned int)g1 << 16),
                      (unsigned int)g2 | ((unsigned int)g3 << 16)};
        *(uint2_a*)&Wh[row * 40 + c4] = hv;
        *(uint2_a*)&Wl[row * 40 + c4] = lv;
        cvt_hilo(xv.x, h0, g0); cvt_hilo(xv.y, h1, g1);
        cvt_hilo(xv.z, h2, g2); cvt_hilo(xv.w, h3, g3);
        uint2_a hv2 = {(unsigned int)h0 | ((unsigned int)h1 << 16),
                       (unsigned int)h2 | ((unsigned int)h3 << 16)};
        uint2_a lv2 = {(unsigned int)g0 | ((unsigned int)g1 << 16),
                       (unsigned int)g2 | ((unsigned int)g3 << 16)};
        *(uint2_a*)&Xh[row * 40 + c4] = hv2;
        *(uint2_a*)&Xl[row * 40 + c4] = lv2;
      }
      __syncthreads();
      const shortx8 xh = *(const shortx8_a*)&Xh[(16 * w + l15) * 40 + 8 * q];
      const shortx8 xl = *(const shortx8_a*)&Xl[(16 * w + l15) * 40 + 8 * q];
#pragma unroll
      for (int nt = 0; nt < 4; ++nt) {
        const shortx8 wh = *(const shortx8_a*)&Wh[(16 * nt + l15) * 40 + 8 * q];
        const shortx8 wl = *(const shortx8_a*)&Wl[(16 * nt + l15) * 40 + 8 * q];
        acc[nt] = __builtin_amdgcn_mfma_f32_16x16x32_bf16(wh, xh, acc[nt], 0, 0, 0);
        acc[nt] = __builtin_amdgcn_mfma_f32_16x16x32_bf16(wh, xl, acc[nt], 0, 0, 0);
        acc[nt] = __builtin_amdgcn_mfma_f32_16x16x32_bf16(wl, xh, acc[nt], 0, 0, 0);
      }
    }
    __syncthreads();
    // lane holds D[n = 16nt+4q+v][m = 16w+l15] -> Ct[n][m]
#pragma unroll
    for (int nt = 0; nt < 4; ++nt)
#pragma unroll
      for (int v = 0; v < 4; ++v)
        Ct[(16 * nt + 4 * q + v) * 68 + 16 * w + l15] = acc[nt][v];
    __syncthreads();
#pragma unroll
    for (int p = 0; p < 4; ++p) {
      const int row = (tid >> 4) + 16 * p;
      const int col4 = (tid & 15) * 4;
      *(float4_a*)&CT[(n0 + row) * S + m0 + col4] = *(const float4_a*)&Ct[row * 68 + col4];
    }
  } else {
    // ---------------- cbkd: c0 = (bid-384)*16 ----------------
    unsigned short* cbs = (unsigned short*)LB;          // [16][136]
    unsigned short* PCc2s = (unsigned short*)(LB + 4352);  // [64][136]
    const int c0 = (bid - 384) << 4;
    // inline PCc2 table build: thread (n=l, seg=w)
    {
      const int n = l, seg = w;
      const float ar = Are[n], ai = Aim[n];
      const float den_re = 1.0f - 0.05f * ar;
      const float den_im = -0.05f * ai;
      const float num_re = 1.0f + 0.05f * ar;
      const float num_im = 0.05f * ai;
      const float inv_d2 = 1.0f / (den_re * den_re + den_im * den_im);
      const float dAr = (num_re * den_re + num_im * den_im) * inv_d2;
      const float dAi = (num_im * den_re - num_re * den_im) * inv_d2;
      float e2r = dAr * dAr - dAi * dAi, e2i = 2.0f * dAr * dAi;
      float e4r = e2r * e2r - e2i * e2i, e4i = 2.0f * e2r * e2i;
      float e8r = e4r * e4r - e4i * e4i, e8i = 2.0f * e4r * e4i;
      float e16r = e8r * e8r - e8i * e8i, e16i = 2.0f * e8r * e8i;
      float br = 1.0f, bi = 0.0f;
      for (int sgo = 0; sgo < seg; ++sgo) {
        const float nr = br * e16r - bi * e16i;
        bi = br * e16i + bi * e16r;
        br = nr;
      }
      float pr = br, pi = bi;
      for (int k = 16 * seg + 1; k <= 16 * seg + 16; ++k) {
        const float nr = pr * dAr - pi * dAi;
        pi = pr * dAi + pi * dAr;
        pr = nr;
        if (k <= 63) {
          PCc2s[k * 136 + n] = f2bf(pr);
          PCc2s[k * 136 + 64 + n] = f2bf(-pi);
        }
      }
      if (seg == 0) {
        PCc2s[n] = f2bf(1.0f);
        PCc2s[64 + n] = 0;
      }
    }
    // cb2 build
#pragma unroll
    for (int ii = 0; ii < 4; ++ii) {
      const int idx = tid + 256 * ii;
      const int ci = idx >> 6, n = idx & 63;
      const int c = c0 + ci;
      const float ar = Are[n], ai = Aim[n];
      const float den_re = 1.0f - 0.05f * ar;
      const float den_im = -0.05f * ai;
      const float inv_d2 = 1.0f / (den_re * den_re + den_im * den_im);
      const float dBr = DT * den_re * inv_d2;
      const float dBi = -DT * den_im * inv_d2;
      const float cr = Cre[c * HID + n], cim = Cim[c * HID + n];
      const unsigned short re = f2bf(2.0f * (cr * dBr - cim * dBi));
      const unsigned short im = f2bf(2.0f * (cr * dBi + cim * dBr));
      cbs[ci * 136 + n] = re;
      cbs[ci * 136 + 64 + n] = im;
      cb2pack[c * 128 + n] = re;
      cb2pack[c * 128 + 64 + n] = im;
    }
    __syncthreads();
    // kd GEMM -> kdpack (kdR layout)
    floatx4 acc = {0.f, 0.f, 0.f, 0.f};
#pragma unroll
    for (int k = 0; k < 4; ++k) {
      const shortx8 a = *(const shortx8_a*)&cbs[l15 * 136 + 8 * q + 32 * k];
      const shortx8 b = *(const shortx8_a*)&PCc2s[(16 * w + l15) * 136 + 8 * q + 32 * k];
      acc = __builtin_amdgcn_mfma_f32_16x16x32_bf16(a, b, acc, 0, 0, 0);
    }
    const int dlt = 16 * w + l15;
#pragma unroll
    for (int v = 0; v < 4; ++v)
      kdpack[(c0 + 4 * q + v) * 128 + 64 - dlt] = f2bf(acc[v]);
    const int row = tid >> 4, p = tid & 15;
#pragma unroll
    for (int k2 = 0; k2 < 4; ++k2) {
      const int idx = p + 16 * k2;
      const int m = (idx == 0) ? 0 : 64 + idx;
      kdpack[(c0 + row) * 128 + m] = 0;
    }
  }
}

// ======= L2: shift SSM, [d][t] domain, taps via scalar loads ================
__global__ __launch_bounds__(256) void shift_ssmT(const float* __restrict__ KrawT,
                                                  const float* __restrict__ Cs,
                                                  const float* __restrict__ Ds,
                                                  float* __restrict__ KnT) {
  __shared__ float kpad[64 + S];
  const int d = blockIdx.x, tid = threadIdx.x;
  if (tid < 64) kpad[tid] = 0.0f;
  *(float4_a*)&kpad[64 + 4 * tid] = *(const float4_a*)&KrawT[d * S + 4 * tid];
  const float dskip = Ds[d];
  const float* taps = Cs + d * HID;  // block-uniform -> scalar loads
  __syncthreads();
  float acc[4];
#pragma unroll
  for (int s = 0; s < 4; ++s) acc[s] = dskip * kpad[64 + tid + 256 * s];
  for (int j = 0; j < 64; ++j) {
    const float tj = taps[j];
#pragma unroll
    for (int s = 0; s < 4; ++s) acc[s] += tj * kpad[64 + tid + 256 * s - j];
  }
#pragma unroll
  for (int s = 0; s < 4; ++s) KnT[d * S + tid + 256 * s] = acc[s];
}

// =============== L3: s4d_fused (inline tables + register scan) ==============
__global__ __launch_bounds__(256) void s4d_fused(
    const float* __restrict__ KnT, const float* __restrict__ VT,
    const float* __restrict__ QT,
    const float* __restrict__ Are, const float* __restrict__ Aim,
    const unsigned short* __restrict__ cb2pack,
    const unsigned short* __restrict__ kdpack,
    const float* __restrict__ Dd, float* __restrict__ OT) {
  __shared__ __align__(16) unsigned short SHu[34368];  // 68736 B
  const int tid = threadIdx.x;
  const int l = tid & 63, w = tid >> 6;
  const int l15 = l & 15, q = l >> 4;
  const int h = blockIdx.x >> 6, j = blockIdx.x & 63;
  const int dv = (h << 6) + j;

  // ---- inline table build: PAre/PAim [n][72], PCc [64][136], dA64 ----
  {
    const int n = l, seg = w;
    unsigned short* PAreW = SHu;
    unsigned short* PAimW = SHu + 4608;
    unsigned short* PCcW = SHu + 9216;
    float_a* dA64W = (float_a*)(SHu + 17920);
    const float ar = Are[n], ai = Aim[n];
    const float den_re = 1.0f - 0.05f * ar;
    const float den_im = -0.05f * ai;
    const float num_re = 1.0f + 0.05f * ar;
    const float num_im = 0.05f * ai;
    const float inv_d2 = 1.0f / (den_re * den_re + den_im * den_im);
    const float dAr = (num_re * den_re + num_im * den_im) * inv_d2;
    const float dAi = (num_im * den_re - num_re * den_im) * inv_d2;
    float e2r = dAr * dAr - dAi * dAi, e2i = 2.0f * dAr * dAi;
    float e4r = e2r * e2r - e2i * e2i, e4i = 2.0f * e2r * e2i;
    float e8r = e4r * e4r - e4i * e4i, e8i = 2.0f * e4r * e4i;
    float e16r = e8r * e8r - e8i * e8i, e16i = 2.0f * e8r * e8i;
    float br = 1.0f, bi = 0.0f;
    for (int sgo = 0; sgo < seg; ++sgo) {
      const float nr = br * e16r - bi * e16i;
      bi = br * e16i + bi * e16r;
      br = nr;
    }
    float pr = br, pi = bi;
    for (int k = 16 * seg + 1; k <= 16 * seg + 16; ++k) {
      const float nr = pr * dAr - pi * dAi;
      pi = pr * dAi + pi * dAr;
      pr = nr;
      if (k <= 63) {
        PAreW[n * 72 + 63 - k] = f2bf(pr);
        PAimW[n * 72 + 63 - k] = f2bf(pi);
      }
      PCcW[(k - 1) * 136 + n] = f2bf(pr);
      PCcW[(k - 1) * 136 + 64 + n] = f2bf(-pi);
      if (k == 64) {
        dA64W[2 * n] = pr;
        dA64W[2 * n + 1] = pi;
      }
    }
    if (seg == 0) {
      PAreW[n * 72 + 63] = f2bf(1.0f);
      PAimW[n * 72 + 63] = 0;
    }
  }
  // ---- V row slice in registers ----
  float4 vvr[4];
#pragma unroll
  for (int s = 0; s < 4; ++s)
    vvr[s] = *(const float4*)&VT[dv * S + 4 * l + 256 * s];

  // ---- initial prefetch (channel i = w) ----
  float4 kx[4], qtv[4];
  float c2r, c2i, dd;
  unsigned int kdv;
  {
    const int i = w;
    const int dk = (h << 6) + i;
    const int c = (h << 12) + (i << 6) + j;
    const int kb = dk * S + 4 * l;
#pragma unroll
    for (int s = 0; s < 4; ++s) {
      kx[s] = *(const float4*)&KnT[kb + 256 * s];
      qtv[s] = *(const float4*)&QT[kb + 256 * s];
    }
    c2r = bf2f(cb2pack[c * 128 + l]);
    c2i = bf2f(cb2pack[c * 128 + 64 + l]);
    kdv = *(const uint_a*)&kdpack[c * 128 + 2 * l];
    dd = Dd[c];
  }
  __syncthreads();

  const unsigned short* PAre = SHu;
  const unsigned short* PAim = SHu + 4608;
  const unsigned short* PCc = SHu + 9216;
  const float_a* dA64v = (const float_a*)(SHu + 17920);
  unsigned short* WB = SHu + 18176 + w * 4048;
  unsigned short* Ub = WB;                    // [16][72] bf16
  unsigned short* SXY = WB + 1152;            // [16][136]: Sc -> Xcb -> yout
  uint_a* kdR32 = (uint_a*)(WB + 3328);       // 68 uints (+pad)
  unsigned short* kdSH = WB + 3472;           // [4][136]
  float_a* yf = (float_a*)SXY;                // [16][68] f32 view

  const float er = dA64v[2 * l], ei = dA64v[2 * l + 1];
  float4 Oa[4];
#pragma unroll
  for (int s = 0; s < 4; ++s) Oa[s] = make_float4(0.f, 0.f, 0.f, 0.f);

#pragma unroll 1
  for (int it = 0; it < 16; ++it) {
    // ---- prefetch next channel ----
    float4 nkx[4], nqt[4];
    float nc2r = 0.f, nc2i = 0.f, ndd = 0.f;
    unsigned int nkdv = 0;
    if (it < 15) {
      const int i = (it + 1) * 4 + w;
      const int dk = (h << 6) + i;
      const int c = (h << 12) + (i << 6) + j;
      const int kb = dk * S + 4 * l;
#pragma unroll
      for (int s = 0; s < 4; ++s) {
        nkx[s] = *(const float4*)&KnT[kb + 256 * s];
        nqt[s] = *(const float4*)&QT[kb + 256 * s];
      }
      nc2r = bf2f(cb2pack[c * 128 + l]);
      nc2i = bf2f(cb2pack[c * 128 + 64 + l]);
      nkdv = *(const uint_a*)&kdpack[c * 128 + 2 * l];
      ndd = Dd[c];
    }

    // ---- 1) u fill ----
#pragma unroll
    for (int s = 0; s < 4; ++s) {
      const int t = 4 * l + 256 * s;
      const int g = t >> 6, r = t & 63;
      uint2_a pp;
      pp.x = (unsigned int)f2bf(kx[s].x * vvr[s].x) | ((unsigned int)f2bf(kx[s].y * vvr[s].y) << 16);
      pp.y = (unsigned int)f2bf(kx[s].z * vvr[s].z) | ((unsigned int)f2bf(kx[s].w * vvr[s].w) << 16);
      *(uint2_a*)&Ub[g * 72 + r] = pp;
    }
    // ---- 2) kdR + 4 shifted copies (mod-4 residues) ----
    kdR32[l] = kdv;
    if (l < 4) kdR32[64 + l] = 0;
    asm volatile("" ::: "memory");
#pragma unroll
    for (int s2 = 0; s2 < 4; ++s2) {
      unsigned int v;
      if (s2 == 0) {
        v = kdR32[l];
      } else if (s2 == 1) {
        v = (kdR32[l] >> 16) | (kdR32[l + 1] << 16);
      } else if (s2 == 2) {
        v = kdR32[l + 1];
      } else {
        v = (kdR32[l + 1] >> 16) | (kdR32[l + 2] << 16);
      }
      *(uint_a*)&kdSH[s2 * 136 + 2 * l] = v;
    }
    asm volatile("" ::: "memory");
    // ---- 3) phase A: s~[g][n] via MFMA ----
    const shortx8 b0 = *(const shortx8_a*)&Ub[l15 * 72 + 8 * q];
    const shortx8 b1 = *(const shortx8_a*)&Ub[l15 * 72 + 8 * q + 32];
#pragma unroll
    for (int tt = 0; tt < 4; ++tt) {
      const int rowb = (tt * 16 + l15) * 72 + 8 * q;
      const shortx8 ar0 = *(const shortx8_a*)&PAre[rowb];
      const shortx8 ar1 = *(const shortx8_a*)&PAre[rowb + 32];
      const shortx8 ai0 = *(const shortx8_a*)&PAim[rowb];
      const shortx8 ai1 = *(const shortx8_a*)&PAim[rowb + 32];
      floatx4 z = {0.f, 0.f, 0.f, 0.f};
      floatx4 sre = __builtin_amdgcn_mfma_f32_16x16x32_bf16(ar0, b0, z, 0, 0, 0);
      sre = __builtin_amdgcn_mfma_f32_16x16x32_bf16(ar1, b1, sre, 0, 0, 0);
      floatx4 sim = __builtin_amdgcn_mfma_f32_16x16x32_bf16(ai0, b0, z, 0, 0, 0);
      sim = __builtin_amdgcn_mfma_f32_16x16x32_bf16(ai1, b1, sim, 0, 0, 0);
      const int sb = l15 * 136 + tt * 16 + 4 * q;
      *(uint_a*)&SXY[sb] = (unsigned int)f2bf(sre[0]) | ((unsigned int)f2bf(sre[1]) << 16);
      *(uint_a*)&SXY[sb + 2] = (unsigned int)f2bf(sre[2]) | ((unsigned int)f2bf(sre[3]) << 16);
      *(uint_a*)&SXY[sb + 64] = (unsigned int)f2bf(sim[0]) | ((unsigned int)f2bf(sim[1]) << 16);
      *(uint_a*)&SXY[sb + 66] = (unsigned int)f2bf(sim[2]) | ((unsigned int)f2bf(sim[3]) << 16);
    }
    asm volatile("" ::: "memory");
    // ---- 4) register scan: batch-load Sc, pure-VALU recurrence ----
    {
      float srr[16], sii[16];
#pragma unroll
      for (int g = 0; g < 16; ++g) {
        srr[g] = bf2f(SXY[g * 136 + l]);
        sii[g] = bf2f(SXY[g * 136 + 64 + l]);
      }
      float xr = 0.f, xi = 0.f;
#pragma unroll
      for (int g = 0; g < 16; ++g) {
        SXY[g * 136 + l] = f2bf(c2r * xr - c2i * xi);
        SXY[g * 136 + 64 + l] = f2bf(c2r * xi + c2i * xr);
        const float nr = er * xr - ei * xi + srr[g];
        xi = er * xi + ei * xr + sii[g];
        xr = nr;
      }
    }
    asm volatile("" ::: "memory");
    // ---- 5) phase C MFMAs ----
    floatx4 acc[4];
#pragma unroll
    for (int tt = 0; tt < 4; ++tt) acc[tt] = (floatx4){0.f, 0.f, 0.f, 0.f};
#pragma unroll
    for (int k = 0; k < 4; ++k) {
      const shortx8 xa = *(const shortx8_a*)&SXY[l15 * 136 + 8 * q + 32 * k];
#pragma unroll
      for (int tt = 0; tt < 4; ++tt) {
        const shortx8 pb = *(const shortx8_a*)&PCc[(tt * 16 + l15) * 136 + 8 * q + 32 * k];
        acc[tt] = __builtin_amdgcn_mfma_f32_16x16x32_bf16(xa, pb, acc[tt], 0, 0, 0);
      }
    }
#pragma unroll
    for (int k = 0; k < 2; ++k) {
      const shortx8 ua = (k == 0) ? b0 : b1;
#pragma unroll
      for (int tt = 0; tt < 4; ++tt) {
        const int r = tt * 16 + l15;
        const int sSh = (4 - (r & 3)) & 3;
        const int addr = sSh * 136 + (64 - r - sSh) + 8 * q + 32 * k;
        const shortx4_a lo = *(const shortx4_a*)&kdSH[addr];
        const shortx4_a hi = *(const shortx4_a*)&kdSH[addr + 4];
        const shortx8 kb8 = __builtin_shufflevector(lo, hi, 0, 1, 2, 3, 4, 5, 6, 7);
        acc[tt] = __builtin_amdgcn_mfma_f32_16x16x32_bf16(ua, kb8, acc[tt], 0, 0, 0);
      }
    }
    // ---- 6) epilogue -> yf ----
#pragma unroll
    for (int tt = 0; tt < 4; ++tt) {
      const int r = tt * 16 + l15;
#pragma unroll
      for (int v = 0; v < 4; ++v) {
        const int g = 4 * q + v;
        yf[g * 68 + r] = acc[tt][v] + dd * bf2f(Ub[g * 72 + r]);
      }
    }
    asm volatile("" ::: "memory");
    // ---- 7) contraction ----
#pragma unroll
    for (int s = 0; s < 4; ++s) {
      const int t = 4 * l + 256 * s;
      const float4_a y4 = *(const float4_a*)&yf[(t >> 6) * 68 + (t & 63)];
      Oa[s].x += qtv[s].x * y4.x;
      Oa[s].y += qtv[s].y * y4.y;
      Oa[s].z += qtv[s].z * y4.z;
      Oa[s].w += qtv[s].w * y4.w;
    }
    asm volatile("" ::: "memory");
#pragma unroll
    for (int s = 0; s < 4; ++s) { kx[s] = nkx[s]; qtv[s] = nqt[s]; }
    c2r = nc2r; c2i = nc2i; kdv = nkdv; dd = ndd;
  }

  // ---- cross-wave reduction of O partials ----
  {
    float_a* Ow = (float_a*)WB;
#pragma unroll
    for (int s = 0; s < 4; ++s) {
      float4_a vv = {Oa[s].x, Oa[s].y, Oa[s].z, Oa[s].w};
      *(float4_a*)&Ow[4 * l + 256 * s] = vv;
    }
  }
  __syncthreads();
  {
    const int tq = 256 * w + 4 * l;
    float4_a acc = {0.f, 0.f, 0.f, 0.f};
#pragma unroll
    for (int w2 = 0; w2 < 4; ++w2) {
      const float_a* Ow2 = (const float_a*)(SHu + 18176 + w2 * 4048);
      acc += *(const float4_a*)&Ow2[tq];
    }
    *(float4_a*)&OT[dv * S + tq] = acc;
  }
}

// ====== L4: out[m][n] = sum_k OT[k][m]*WO[n][k] via bf16 hi/lo MFMA =========
__global__ __launch_bounds__(256) void gemm_outT(const float* __restrict__ OT,
                                                 const float* __restrict__ WO,
                                                 float* __restrict__ out) {
  __shared__ __align__(16) char LB[20480];
  unsigned short* Wh = (unsigned short*)LB;  // [64][40] WO planes
  unsigned short* Wl = Wh + 2560;
  unsigned short* Xh = Wl + 2560;            // [64][40] O1 planes (m rows)
  unsigned short* Xl = Xh + 2560;
  float_a* Ct = (float_a*)LB;                // [64][68] aliased
  const int tid = threadIdx.x;
  const int l = tid & 63, w = tid >> 6;
  const int l15 = l & 15, q = l >> 4;
  const int n0 = (blockIdx.x & 7) * 64, m0 = (blockIdx.x >> 3) * 64;

  floatx4 acc[4];
#pragma unroll
  for (int nt = 0; nt < 4; ++nt) acc[nt] = (floatx4){0.f, 0.f, 0.f, 0.f};

  for (int k0 = 0; k0 < D; k0 += 32) {
    if (k0) __syncthreads();
#pragma unroll
    for (int p = 0; p < 2; ++p) {
      const int idx = tid + 256 * p;
      // WO rows (n-local), k-contiguous
      {
        const int row = idx >> 3, c4 = (idx & 7) * 4;
        const float4 wv = *(const float4*)&WO[(n0 + row) * D + k0 + c4];
        unsigned short h0, h1, h2, h3, g0, g1, g2, g3;
        cvt_hilo(wv.x, h0, g0); cvt_hilo(wv.y, h1, g1);
        cvt_hilo(wv.z, h2, g2); cvt_hilo(wv.w, h3, g3);
        uint2_a hv = {(unsigned int)h0 | ((unsigned int)h1 << 16),
                      (unsigned int)h2 | ((unsigned int)h3 << 16)};
        uint2_a lv = {(unsigned int)g0 | ((unsigned int)g1 << 16),
                      (unsigned int)g2 | ((unsigned int)g3 << 16)};
        *(uint2_a*)&Wh[row * 40 + c4] = hv;
        *(uint2_a*)&Wl[row * 40 + c4] = lv;
      }
      // OT tile: read [k][m] coalesced, store transposed [m][k]
      {
        const int kk = idx >> 4, m4 = (idx & 15) * 4;
        const float4 ov = *(const float4*)&OT[(k0 + kk) * S + m0 + m4];
        unsigned short h, g;
        cvt_hilo(ov.x, h, g); Xh[(m4 + 0) * 40 + kk] = h; Xl[(m4 + 0) * 40 + kk] = g;
        cvt_hilo(ov.y, h, g); Xh[(m4 + 1) * 40 + kk] = h; Xl[(m4 + 1) * 40 + kk] = g;
        cvt_hilo(ov.z, h, g); Xh[(m4 + 2) * 40 + kk] = h; Xl[(m4 + 2) * 40 + kk] = g;
        cvt_hilo(ov.w, h, g); Xh[(m4 + 3) * 40 + kk] = h; Xl[(m4 + 3) * 40 + kk] = g;
      }
    }
    __syncthreads();
    const shortx8 xh = *(const shortx8_a*)&Xh[(16 * w + l15) * 40 + 8 * q];
    const shortx8 xl = *(const shortx8_a*)&Xl[(16 * w + l15) * 40 + 8 * q];
#pragma unroll
    for (int nt = 0; nt < 4; ++nt) {
      const shortx8 wh = *(const shortx8_a*)&Wh[(16 * nt + l15) * 40 + 8 * q];
      const shortx8 wl = *(const shortx8_a*)&Wl[(16 * nt + l15) * 40 + 8 * q];
      acc[nt] = __builtin_amdgcn_mfma_f32_16x16x32_bf16(wh, xh, acc[nt], 0, 0, 0);
      acc[nt] = __builtin_amdgcn_mfma_f32_16x16x32_bf16(wh, xl, acc[nt], 0, 0, 0);
      acc[nt] = __builtin_amdgcn_mfma_f32_16x16x32_bf16(wl, xh, acc[nt], 0, 0, 0);
    }
  }
  __syncthreads();
  // lane holds D[n = 16nt+4q+v][m = 16w+l15] -> Ct[m][n]
#pragma unroll
  for (int nt = 0; nt < 4; ++nt)
#pragma unroll
    for (int v = 0; v < 4; ++v)
      Ct[(16 * w + l15) * 68 + 16 * nt + 4 * q + v] = acc[nt][v];
  __syncthreads();
#pragma unroll
  for (int p = 0; p < 4; ++p) {
    const int row = (tid >> 4) + 16 * p;
    const int col4 = (tid & 15) * 4;
    *(float4_a*)&out[(m0 + row) * D + n0 + col4] = *(const float4_a*)&Ct[row * 68 + col4];
  }
}

extern "C" void kernel_launch(void* const* d_in, const int* in_sizes, int n_in,
                              void* d_out, int out_size, void* d_ws, size_t ws_size,
                              hipStream_t stream) {
  const float* x   = (const float*)d_in[0];
  const float* WQ  = (const float*)d_in[1];
  const float* WK  = (const float*)d_in[2];
  const float* WV  = (const float*)d_in[3];
  const float* WO  = (const float*)d_in[4];
  const float* Cs  = (const float*)d_in[5];
  const float* Ds  = (const float*)d_in[6];
  const float* Are = (const float*)d_in[7];
  const float* Aim = (const float*)d_in[8];
  const float* Cre = (const float*)d_in[9];
  const float* Cim = (const float*)d_in[10];
  const float* Dd  = (const float*)d_in[11];
  float* out = (float*)d_out;

  char* ws = (char*)d_ws;
  const size_t SD = (size_t)S * D * 4;   // 2 MB
  float* QT    = (float*)(ws + 0 * SD);
  float* KrawT = (float*)(ws + 1 * SD);
  float* VT    = (float*)(ws + 2 * SD);
  float* KnT   = (float*)(ws + 3 * SD);
  float* OT    = (float*)(ws + 4 * SD);
  unsigned short* cb2pack = (unsigned short*)(ws + 5 * SD);            // 8 MB
  unsigned short* kdpack  = (unsigned short*)(ws + 5 * SD + 8388608);  // 8 MB

  fused_qkv_cbkd<<<384 + CD / 16, 256, 0, stream>>>(
      x, WQ, WK, WV, Are, Aim, Cre, Cim, QT, KrawT, VT, cb2pack, kdpack);
  shift_ssmT<<<512, 256, 0, stream>>>(KrawT, Cs, Ds, KnT);
  s4d_fused<<<512, 256, 0, stream>>>(KnT, VT, QT, Are, Aim, cb2pack, kdpack, Dd, OT);
  gemm_outT<<<128, 256, 0, stream>>>(OT, WO, out);
}